// Round 1
// baseline (1815.040 us; speedup 1.0000x reference)
//
#include <hip/hip_runtime.h>

constexpr int NN    = 100000;
constexpr int NE    = 1200000;
constexpr int D_IN  = 64;
constexpr int D_HID = 64;
constexpr int D_OUT = 32;

// ---- degree via float atomics (shared by both layers) ----
__global__ __launch_bounds__(256) void k_deg(const int* __restrict__ dst,
                                             float* __restrict__ deg, int E) {
    int i = blockIdx.x * 256 + threadIdx.x;
    if (i < E) atomicAdd(&deg[dst[i]], 1.0f);
}

// ---- scatter: S[dst[e]*W + q*4 .. +3] += Z[src[e]*W + q*4 .. +3] ----
template<int W>
__global__ __launch_bounds__(256) void k_scatter(const int* __restrict__ src,
                                                 const int* __restrict__ dst,
                                                 const float* __restrict__ Z,
                                                 float* __restrict__ S, int E) {
    constexpr int TPE = W / 4;  // threads per edge, float4 each
    long long gid = (long long)blockIdx.x * 256 + threadIdx.x;
    int e = (int)(gid / TPE);
    int q = (int)(gid % TPE);
    if (e >= E) return;
    int s = src[e], d = dst[e];
    const float4 v = *reinterpret_cast<const float4*>(Z + (size_t)s * W + q * 4);
    float* p = S + (size_t)d * W + q * 4;
    atomicAdd(p + 0, v.x);
    atomicAdd(p + 1, v.y);
    atomicAdd(p + 2, v.z);
    atomicAdd(p + 3, v.w);
}

// ---- Y = A[n_rows x KI] @ W[KI x KO], W staged in LDS ----
template<int KI, int KO>
__global__ __launch_bounds__(256) void k_gemm(const float* __restrict__ A,
                                              const float* __restrict__ W,
                                              float* __restrict__ Y, int n_rows) {
    __shared__ float Wl[KI * KO];
    for (int i = threadIdx.x; i < KI * KO; i += 256) Wl[i] = W[i];
    __syncthreads();
    constexpr int RPB = 256 / KO;
    int r = blockIdx.x * RPB + threadIdx.x / KO;
    int j = threadIdx.x % KO;
    if (r >= n_rows) return;
    const float* a = A + (size_t)r * KI;
    float acc = 0.f;
#pragma unroll
    for (int k = 0; k < KI; ++k) acc = fmaf(a[k], Wl[k * KO + j], acc);
    Y[(size_t)r * KO + j] = acc;
}

// ---- fused output:
//   PRE=false: out = A@Wself + inv(deg)*(S@Wneigh) + b    (S width KI, raw scatter)
//   PRE=true : out = A@Wself + inv(deg)*S + b             (S width KO, pre-transformed)
template<int KI, int KO, bool PRE>
__global__ __launch_bounds__(256) void k_final(const float* __restrict__ A,
                                               const float* __restrict__ Wself,
                                               const float* __restrict__ S,
                                               const float* __restrict__ Wneigh,
                                               const float* __restrict__ deg,
                                               const float* __restrict__ b,
                                               float* __restrict__ out, int n_rows) {
    __shared__ float Ws[KI * KO];
    __shared__ float Wn[PRE ? 1 : (KI * KO)];
    for (int i = threadIdx.x; i < KI * KO; i += 256) Ws[i] = Wself[i];
    if (!PRE)
        for (int i = threadIdx.x; i < KI * KO; i += 256) Wn[i] = Wneigh[i];
    __syncthreads();
    constexpr int RPB = 256 / KO;
    int r = blockIdx.x * RPB + threadIdx.x / KO;
    int j = threadIdx.x % KO;
    if (r >= n_rows) return;
    const float* a = A + (size_t)r * KI;
    float acc = 0.f;
#pragma unroll
    for (int k = 0; k < KI; ++k) acc = fmaf(a[k], Ws[k * KO + j], acc);
    float inv = 1.0f / fmaxf(deg[r], 1.0f);
    float nacc;
    if (PRE) {
        nacc = S[(size_t)r * KO + j];
    } else {
        const float* s = S + (size_t)r * KI;
        nacc = 0.f;
#pragma unroll
        for (int k = 0; k < KI; ++k) nacc = fmaf(s[k], Wn[k * KO + j], nacc);
    }
    out[(size_t)r * KO + j] = acc + inv * nacc + b[j];
}

extern "C" void kernel_launch(void* const* d_in, const int* in_sizes, int n_in,
                              void* d_out, int out_size, void* d_ws, size_t ws_size,
                              hipStream_t stream) {
    const float* feat    = (const float*)d_in[0];
    const int*   src     = (const int*)d_in[1];
    const int*   dst     = (const int*)d_in[2];
    const float* Wself1  = (const float*)d_in[3];
    const float* Wneigh1 = (const float*)d_in[4];
    const float* b1      = (const float*)d_in[5];
    const float* Wself2  = (const float*)d_in[6];
    const float* Wneigh2 = (const float*)d_in[7];
    const float* b2      = (const float*)d_in[8];
    float* out = (float*)d_out;

    char* ws = (char*)d_ws;
    size_t off = 0;
    auto alloc = [&](size_t bytes) -> void* {
        void* p = ws + off;
        off += (bytes + 255) & ~(size_t)255;
        return p;
    };
    float* deg = (float*)alloc((size_t)NN * sizeof(float));           // N
    float* S   = (float*)alloc((size_t)NN * D_HID * sizeof(float));   // N*64 (reused as Z2|S2 in L2)
    float* h1  = (float*)alloc((size_t)NN * D_HID * sizeof(float));   // N*64

    // degrees
    hipMemsetAsync(deg, 0, (size_t)NN * sizeof(float), stream);
    k_deg<<<(NE + 255) / 256, 256, 0, stream>>>(dst, deg, NE);

    // ---- layer 1: scatter raw features (64-wide), fused double-GEMM ----
    hipMemsetAsync(S, 0, (size_t)NN * D_IN * sizeof(float), stream);
    {
        long long tot = (long long)NE * (D_IN / 4);
        k_scatter<D_IN><<<(int)((tot + 255) / 256), 256, 0, stream>>>(src, dst, feat, S, NE);
    }
    k_final<D_IN, D_HID, false><<<(NN + 3) / 4, 256, 0, stream>>>(
        feat, Wself1, S, Wneigh1, deg, b1, h1, NN);

    // ---- layer 2: transform-then-scatter (32-wide) ----
    float* Z2 = S;                            // N*32
    float* S2 = S + (size_t)NN * D_OUT;       // N*32
    k_gemm<D_HID, D_OUT><<<(NN + 7) / 8, 256, 0, stream>>>(h1, Wneigh2, Z2, NN);
    hipMemsetAsync(S2, 0, (size_t)NN * D_OUT * sizeof(float), stream);
    {
        long long tot = (long long)NE * (D_OUT / 4);
        k_scatter<D_OUT><<<(int)((tot + 255) / 256), 256, 0, stream>>>(src, dst, Z2, S2, NE);
    }
    k_final<D_HID, D_OUT, true><<<(NN + 7) / 8, 256, 0, stream>>>(
        h1, Wself2, S2, nullptr, deg, b2, out, NN);
}

// Round 2
// 623.628 us; speedup vs baseline: 2.9105x; 2.9105x over previous
//
#include <hip/hip_runtime.h>

constexpr int NN    = 100000;
constexpr int NE    = 1200000;
constexpr int D_IN  = 64;
constexpr int D_HID = 64;
constexpr int D_OUT = 32;

// ---- 1) histogram of dst ----
__global__ __launch_bounds__(256) void k_hist(const int* __restrict__ dst,
                                              int* __restrict__ cnt, int E) {
    int i = blockIdx.x * 256 + threadIdx.x;
    if (i < E) atomicAdd(&cnt[dst[i]], 1);
}

// ---- 2) exclusive scan of cnt[0..n) -> off[0..n], off[n]=total ----
// scan1: per-block (1024 elems) totals
__global__ __launch_bounds__(256) void k_scan1(const int* __restrict__ cnt,
                                               int* __restrict__ bsum, int n) {
    __shared__ int lds[256];
    int base = blockIdx.x * 1024;
    int t = threadIdx.x;
    int s = 0;
#pragma unroll
    for (int u = 0; u < 4; ++u) {
        int i = base + t * 4 + u;
        if (i < n) s += cnt[i];
    }
    lds[t] = s;
    __syncthreads();
    for (int w = 128; w > 0; w >>= 1) {
        if (t < w) lds[t] += lds[t + w];
        __syncthreads();
    }
    if (t == 0) bsum[blockIdx.x] = lds[0];
}

// scan2: single block, exclusive scan of block sums (nb <= 128)
__global__ __launch_bounds__(128) void k_scan2(int* __restrict__ bsum, int nb) {
    __shared__ int lds[128];
    int t = threadIdx.x;
    lds[t] = (t < nb) ? bsum[t] : 0;
    __syncthreads();
    for (int d = 1; d < 128; d <<= 1) {
        int v = (t >= d) ? lds[t - d] : 0;
        __syncthreads();
        lds[t] += v;
        __syncthreads();
    }
    if (t < nb) bsum[t] = (t == 0) ? 0 : lds[t - 1];
}

// scan3: per-block exclusive scan + block offset -> off; off[n] = total
__global__ __launch_bounds__(256) void k_scan3(const int* __restrict__ cnt,
                                               const int* __restrict__ bsum,
                                               int* __restrict__ off, int n) {
    __shared__ int lds[256];
    int base = blockIdx.x * 1024;
    int t = threadIdx.x;
    int v[4];
    int s = 0;
#pragma unroll
    for (int u = 0; u < 4; ++u) {
        int i = base + t * 4 + u;
        v[u] = (i < n) ? cnt[i] : 0;
        s += v[u];
    }
    lds[t] = s;
    __syncthreads();
    for (int d = 1; d < 256; d <<= 1) {
        int x = (t >= d) ? lds[t - d] : 0;
        __syncthreads();
        lds[t] += x;
        __syncthreads();
    }
    int excl = bsum[blockIdx.x] + ((t == 0) ? 0 : lds[t - 1]);
#pragma unroll
    for (int u = 0; u < 4; ++u) {
        int i = base + t * 4 + u;
        if (i < n) off[i] = excl;
        excl += v[u];
    }
    if (blockIdx.x == gridDim.x - 1 && t == 255) off[n] = excl;  // grand total
}

// ---- 3) place each edge's src into its dst bucket ----
__global__ __launch_bounds__(256) void k_pos(const int* __restrict__ src,
                                             const int* __restrict__ dst,
                                             int* __restrict__ cur,
                                             int* __restrict__ esrc, int E) {
    int e = blockIdx.x * 256 + threadIdx.x;
    if (e < E) {
        int p = atomicAdd(&cur[dst[e]], 1);
        esrc[p] = src[e];
    }
}

// ---- 4) gather-mean: H[r][lane] = mean over in-edges of Z[esrc][lane] ----
template<int W>
__global__ __launch_bounds__(256) void k_gather(const int* __restrict__ off,
                                                const int* __restrict__ esrc,
                                                const float* __restrict__ Z,
                                                float* __restrict__ H, int n) {
    int grp  = (blockIdx.x * 256 + threadIdx.x) / W;
    int lane = threadIdx.x % W;
    if (grp >= n) return;
    int beg = off[grp], end = off[grp + 1];
    float acc = 0.f;
    for (int k = beg; k < end; ++k) {
        int s = esrc[k];  // wave-uniform -> broadcast
        acc += Z[(size_t)s * W + lane];
    }
    float inv = (end > beg) ? 1.0f / (float)(end - beg) : 0.f;
    H[(size_t)grp * W + lane] = acc * inv;
}

// ---- Y = A[n x KI] @ W[KI x KO], weights in LDS ----
template<int KI, int KO>
__global__ __launch_bounds__(256) void k_gemm(const float* __restrict__ A,
                                              const float* __restrict__ W,
                                              float* __restrict__ Y, int n_rows) {
    __shared__ float Wl[KI * KO];
    for (int i = threadIdx.x; i < KI * KO; i += 256) Wl[i] = W[i];
    __syncthreads();
    constexpr int RPB = 256 / KO;
    int r = blockIdx.x * RPB + threadIdx.x / KO;
    int j = threadIdx.x % KO;
    if (r >= n_rows) return;
    const float* a = A + (size_t)r * KI;
    float acc = 0.f;
#pragma unroll
    for (int k = 0; k < KI; ++k) acc = fmaf(a[k], Wl[k * KO + j], acc);
    Y[(size_t)r * KO + j] = acc;
}

// ---- fused output (S already mean-normalized):
//   PRE=false: out = A@Wself + S@Wneigh + b     (S width KI)
//   PRE=true : out = A@Wself + S + b            (S width KO, pre-transformed)
template<int KI, int KO, bool PRE>
__global__ __launch_bounds__(256) void k_final(const float* __restrict__ A,
                                               const float* __restrict__ Wself,
                                               const float* __restrict__ S,
                                               const float* __restrict__ Wneigh,
                                               const float* __restrict__ b,
                                               float* __restrict__ out, int n_rows) {
    __shared__ float Ws[KI * KO];
    __shared__ float Wn[PRE ? 1 : (KI * KO)];
    for (int i = threadIdx.x; i < KI * KO; i += 256) Ws[i] = Wself[i];
    if (!PRE)
        for (int i = threadIdx.x; i < KI * KO; i += 256) Wn[i] = Wneigh[i];
    __syncthreads();
    constexpr int RPB = 256 / KO;
    int r = blockIdx.x * RPB + threadIdx.x / KO;
    int j = threadIdx.x % KO;
    if (r >= n_rows) return;
    const float* a = A + (size_t)r * KI;
    float acc = 0.f;
#pragma unroll
    for (int k = 0; k < KI; ++k) acc = fmaf(a[k], Ws[k * KO + j], acc);
    float nacc;
    if (PRE) {
        nacc = S[(size_t)r * KO + j];
    } else {
        const float* s = S + (size_t)r * KI;
        nacc = 0.f;
#pragma unroll
        for (int k = 0; k < KI; ++k) nacc = fmaf(s[k], Wn[k * KO + j], nacc);
    }
    out[(size_t)r * KO + j] = acc + nacc + b[j];
}

extern "C" void kernel_launch(void* const* d_in, const int* in_sizes, int n_in,
                              void* d_out, int out_size, void* d_ws, size_t ws_size,
                              hipStream_t stream) {
    const float* feat    = (const float*)d_in[0];
    const int*   src     = (const int*)d_in[1];
    const int*   dst     = (const int*)d_in[2];
    const float* Wself1  = (const float*)d_in[3];
    const float* Wneigh1 = (const float*)d_in[4];
    const float* b1      = (const float*)d_in[5];
    const float* Wself2  = (const float*)d_in[6];
    const float* Wneigh2 = (const float*)d_in[7];
    const float* b2      = (const float*)d_in[8];
    float* out = (float*)d_out;

    char* ws = (char*)d_ws;
    size_t offb = 0;
    auto alloc = [&](size_t bytes) -> void* {
        void* p = ws + offb;
        offb += (bytes + 255) & ~(size_t)255;
        return p;
    };
    int*   cnt  = (int*)alloc((size_t)NN * sizeof(int));            // hist, later cursor
    int*   off  = (int*)alloc((size_t)(NN + 1) * sizeof(int));      // CSR offsets
    int*   bsum = (int*)alloc(128 * sizeof(int));                   // scan block sums
    int*   esrc = (int*)alloc((size_t)NE * sizeof(int));            // sorted-by-dst src ids
    float* S    = (float*)alloc((size_t)NN * D_HID * sizeof(float)); // agg (reused L2: Z2|S2)
    float* h1   = (float*)alloc((size_t)NN * D_HID * sizeof(float)); // layer-1 output

    constexpr int NB = (NN + 1023) / 1024;  // 98 scan blocks

    // ---- build CSR by dst (counting sort) ----
    hipMemsetAsync(cnt, 0, (size_t)NN * sizeof(int), stream);
    k_hist<<<(NE + 255) / 256, 256, 0, stream>>>(dst, cnt, NE);
    k_scan1<<<NB, 256, 0, stream>>>(cnt, bsum, NN);
    k_scan2<<<1, 128, 0, stream>>>(bsum, NB);
    k_scan3<<<NB, 256, 0, stream>>>(cnt, bsum, off, NN);
    hipMemcpyAsync(cnt, off, (size_t)NN * sizeof(int), hipMemcpyDeviceToDevice, stream);
    k_pos<<<(NE + 255) / 256, 256, 0, stream>>>(src, dst, cnt, esrc, NE);

    // ---- layer 1: gather-mean raw features (64-wide) + fused double GEMM ----
    k_gather<D_IN><<<(NN * D_IN + 255) / 256, 256, 0, stream>>>(off, esrc, feat, S, NN);
    k_final<D_IN, D_HID, false><<<(NN + 3) / 4, 256, 0, stream>>>(
        feat, Wself1, S, Wneigh1, b1, h1, NN);

    // ---- layer 2: transform (64->32) then gather-mean (32-wide) ----
    float* Z2 = S;                       // N*32
    float* S2 = S + (size_t)NN * D_OUT;  // N*32
    k_gemm<D_HID, D_OUT><<<(NN + 7) / 8, 256, 0, stream>>>(h1, Wneigh2, Z2, NN);
    k_gather<D_OUT><<<(NN * D_OUT + 255) / 256, 256, 0, stream>>>(off, esrc, Z2, S2, NN);
    k_final<D_HID, D_OUT, true><<<(NN + 7) / 8, 256, 0, stream>>>(
        h1, Wself2, S2, nullptr, b2, out, NN);
}

// Round 3
// 296.708 us; speedup vs baseline: 6.1173x; 2.1018x over previous
//
#include <hip/hip_runtime.h>

constexpr int NN    = 100000;
constexpr int NE    = 1200000;
constexpr int D_IN  = 64;
constexpr int D_HID = 64;
constexpr int D_OUT = 32;

typedef float  f32x4 __attribute__((ext_vector_type(4)));
typedef short  s16x8 __attribute__((ext_vector_type(8)));

static __device__ __forceinline__ unsigned short f2b(float f) {
    unsigned int u = __float_as_uint(f);
    u = (u + 0x7FFFu + ((u >> 16) & 1u)) >> 16;   // RNE
    return (unsigned short)u;
}
static __device__ __forceinline__ float b2f(unsigned short h) {
    return __uint_as_float((unsigned int)h << 16);
}

// ================= CSR build =================
__global__ __launch_bounds__(256) void k_hist(const int* __restrict__ dst,
                                              int* __restrict__ cnt, int E) {
    int i = blockIdx.x * 256 + threadIdx.x;
    if (i < E) atomicAdd(&cnt[dst[i]], 1);
}

__global__ __launch_bounds__(256) void k_scan1(const int* __restrict__ cnt,
                                               int* __restrict__ bsum, int n) {
    __shared__ int lds[256];
    int base = blockIdx.x * 1024;
    int t = threadIdx.x;
    int s = 0;
#pragma unroll
    for (int u = 0; u < 4; ++u) {
        int i = base + t * 4 + u;
        if (i < n) s += cnt[i];
    }
    lds[t] = s;
    __syncthreads();
    for (int w = 128; w > 0; w >>= 1) {
        if (t < w) lds[t] += lds[t + w];
        __syncthreads();
    }
    if (t == 0) bsum[blockIdx.x] = lds[0];
}

__global__ __launch_bounds__(128) void k_scan2(int* __restrict__ bsum, int nb) {
    __shared__ int lds[128];
    int t = threadIdx.x;
    lds[t] = (t < nb) ? bsum[t] : 0;
    __syncthreads();
    for (int d = 1; d < 128; d <<= 1) {
        int v = (t >= d) ? lds[t - d] : 0;
        __syncthreads();
        lds[t] += v;
        __syncthreads();
    }
    if (t < nb) bsum[t] = (t == 0) ? 0 : lds[t - 1];
}

__global__ __launch_bounds__(256) void k_scan3(const int* __restrict__ cnt,
                                               const int* __restrict__ bsum,
                                               int* __restrict__ off, int n) {
    __shared__ int lds[256];
    int base = blockIdx.x * 1024;
    int t = threadIdx.x;
    int v[4];
    int s = 0;
#pragma unroll
    for (int u = 0; u < 4; ++u) {
        int i = base + t * 4 + u;
        v[u] = (i < n) ? cnt[i] : 0;
        s += v[u];
    }
    lds[t] = s;
    __syncthreads();
    for (int d = 1; d < 256; d <<= 1) {
        int x = (t >= d) ? lds[t - d] : 0;
        __syncthreads();
        lds[t] += x;
        __syncthreads();
    }
    int excl = bsum[blockIdx.x] + ((t == 0) ? 0 : lds[t - 1]);
#pragma unroll
    for (int u = 0; u < 4; ++u) {
        int i = base + t * 4 + u;
        if (i < n) off[i] = excl;
        excl += v[u];
    }
    if (blockIdx.x == gridDim.x - 1 && t == 255) off[n] = excl;
}

__global__ __launch_bounds__(256) void k_pos(const int* __restrict__ src,
                                             const int* __restrict__ dst,
                                             int* __restrict__ cur,
                                             int* __restrict__ esrc, int E) {
    int e = blockIdx.x * 256 + threadIdx.x;
    if (e < E) {
        int p = atomicAdd(&cur[dst[e]], 1);
        esrc[p] = src[e];
    }
}

// ================= MFMA GEMM 1: C1[N x 128](bf16) = feat @ [Ws1|Wn1] (+b1 on cols<64) ====
// block = 256 thr (4 waves), 64 rows/block, wave w -> rows blk*64 + w*16
__global__ __launch_bounds__(256) void k_mfma1(const float* __restrict__ feat,
                                               const float* __restrict__ Ws,
                                               const float* __restrict__ Wn,
                                               const float* __restrict__ b,
                                               unsigned short* __restrict__ C1) {
    __shared__ unsigned short Bl[16 * 64 * 8];  // [frag=ct*2+kt][lane][8] 16KB
    const int tid = threadIdx.x;
    // stage B in fragment order (bf16)
    for (int idx = tid; idx < 16 * 64; idx += 256) {
        int frag = idx >> 6, le = idx & 63;
        int ct = frag >> 1, kt = frag & 1;
        int col = ct * 16 + (le & 15);
        int kb  = kt * 32 + (le >> 4) * 8;
        unsigned short tmp[8];
#pragma unroll
        for (int j = 0; j < 8; ++j) {
            int k = kb + j;
            float w = (col < 64) ? Ws[k * 64 + col] : Wn[k * 64 + (col - 64)];
            tmp[j] = f2b(w);
        }
        uint4 pk;
        pk.x = (unsigned)tmp[0] | ((unsigned)tmp[1] << 16);
        pk.y = (unsigned)tmp[2] | ((unsigned)tmp[3] << 16);
        pk.z = (unsigned)tmp[4] | ((unsigned)tmp[5] << 16);
        pk.w = (unsigned)tmp[6] | ((unsigned)tmp[7] << 16);
        *(uint4*)(&Bl[idx * 8]) = pk;
    }
    __syncthreads();

    const int wave = tid >> 6, lane = tid & 63;
    const int r0 = blockIdx.x * 64 + wave * 16;

    // A frags (2 k-tiles) from global f32, convert to bf16
    s16x8 a[2];
#pragma unroll
    for (int kt = 0; kt < 2; ++kt) {
        int row = r0 + (lane & 15);
        if (row >= NN) row = NN - 1;
        int kb = kt * 32 + (lane >> 4) * 8;
        const float4 f0 = *(const float4*)(feat + (size_t)row * 64 + kb);
        const float4 f1 = *(const float4*)(feat + (size_t)row * 64 + kb + 4);
        a[kt][0] = (short)f2b(f0.x); a[kt][1] = (short)f2b(f0.y);
        a[kt][2] = (short)f2b(f0.z); a[kt][3] = (short)f2b(f0.w);
        a[kt][4] = (short)f2b(f1.x); a[kt][5] = (short)f2b(f1.y);
        a[kt][6] = (short)f2b(f1.z); a[kt][7] = (short)f2b(f1.w);
    }

    const s16x8* Bl8 = (const s16x8*)Bl;
#pragma unroll
    for (int ct = 0; ct < 8; ++ct) {
        f32x4 acc = {0.f, 0.f, 0.f, 0.f};
#pragma unroll
        for (int kt = 0; kt < 2; ++kt) {
            s16x8 bf = Bl8[(ct * 2 + kt) * 64 + lane];
            acc = __builtin_amdgcn_mfma_f32_16x16x32_bf16(a[kt], bf, acc, 0, 0, 0);
        }
        int c = ct * 16 + (lane & 15);
        float bias = (c < 64) ? b[c] : 0.f;
#pragma unroll
        for (int q = 0; q < 4; ++q) {
            int r = r0 + (lane >> 4) * 4 + q;
            if (r < NN) C1[(size_t)r * 128 + c] = f2b(acc[q] + bias);
        }
    }
}

// ===== MFMA GEMM 2: [C2s f32 | C2n bf16] (N x 32 each) = h1(bf16) @ [Ws2|Wn2] (+b2 on self)
__global__ __launch_bounds__(256) void k_mfma2(const unsigned short* __restrict__ h1,
                                               const float* __restrict__ Ws,
                                               const float* __restrict__ Wn,
                                               const float* __restrict__ b,
                                               float* __restrict__ C2s,
                                               unsigned short* __restrict__ C2n) {
    __shared__ unsigned short Bl[8 * 64 * 8];  // 8KB
    const int tid = threadIdx.x;
    for (int idx = tid; idx < 8 * 64; idx += 256) {
        int frag = idx >> 6, le = idx & 63;
        int ct = frag >> 1, kt = frag & 1;
        int col = ct * 16 + (le & 15);
        int kb  = kt * 32 + (le >> 4) * 8;
        unsigned short tmp[8];
#pragma unroll
        for (int j = 0; j < 8; ++j) {
            int k = kb + j;
            float w = (col < 32) ? Ws[k * 32 + col] : Wn[k * 32 + (col - 32)];
            tmp[j] = f2b(w);
        }
        uint4 pk;
        pk.x = (unsigned)tmp[0] | ((unsigned)tmp[1] << 16);
        pk.y = (unsigned)tmp[2] | ((unsigned)tmp[3] << 16);
        pk.z = (unsigned)tmp[4] | ((unsigned)tmp[5] << 16);
        pk.w = (unsigned)tmp[6] | ((unsigned)tmp[7] << 16);
        *(uint4*)(&Bl[idx * 8]) = pk;
    }
    __syncthreads();

    const int wave = tid >> 6, lane = tid & 63;
    const int r0 = blockIdx.x * 64 + wave * 16;

    s16x8 a[2];
#pragma unroll
    for (int kt = 0; kt < 2; ++kt) {
        int row = r0 + (lane & 15);
        if (row >= NN) row = NN - 1;
        int kb = kt * 32 + (lane >> 4) * 8;
        a[kt] = *(const s16x8*)(h1 + (size_t)row * 64 + kb);
    }

    const s16x8* Bl8 = (const s16x8*)Bl;
#pragma unroll
    for (int ct = 0; ct < 4; ++ct) {
        f32x4 acc = {0.f, 0.f, 0.f, 0.f};
#pragma unroll
        for (int kt = 0; kt < 2; ++kt) {
            s16x8 bf = Bl8[(ct * 2 + kt) * 64 + lane];
            acc = __builtin_amdgcn_mfma_f32_16x16x32_bf16(a[kt], bf, acc, 0, 0, 0);
        }
        int c = ct * 16 + (lane & 15);
#pragma unroll
        for (int q = 0; q < 4; ++q) {
            int r = r0 + (lane >> 4) * 4 + q;
            if (r < NN) {
                if (c < 32) C2s[(size_t)r * 32 + c] = acc[q] + b[c];
                else        C2n[(size_t)r * 32 + (c - 32)] = f2b(acc[q]);
            }
        }
    }
}

// ===== gather 1: h1[r] (bf16, width64) = C1self[r] + mean_k C1neigh[esrc[k]] =====
// 32 lanes per node (each lane: u32 = 2 bf16), 8 nodes/block
__global__ __launch_bounds__(256) void k_gath1(const int* __restrict__ off,
                                               const int* __restrict__ esrc,
                                               const unsigned short* __restrict__ C1,
                                               unsigned short* __restrict__ h1) {
    int node = blockIdx.x * 8 + (threadIdx.x >> 5);
    int sub  = threadIdx.x & 31;
    if (node >= NN) return;
    int beg = off[node], end = off[node + 1];
    float a0 = 0.f, a1 = 0.f;
    for (int k = beg; k < end; ++k) {
        int s = esrc[k];
        unsigned int v = *(const unsigned int*)(C1 + (size_t)s * 128 + 64 + sub * 2);
        a0 += b2f((unsigned short)(v & 0xFFFF));
        a1 += b2f((unsigned short)(v >> 16));
    }
    float inv = (end > beg) ? 1.0f / (float)(end - beg) : 0.f;
    unsigned int sv = *(const unsigned int*)(C1 + (size_t)node * 128 + sub * 2);
    float h0 = b2f((unsigned short)(sv & 0xFFFF)) + a0 * inv;
    float h1v = b2f((unsigned short)(sv >> 16)) + a1 * inv;
    unsigned int o = (unsigned int)f2b(h0) | ((unsigned int)f2b(h1v) << 16);
    *(unsigned int*)(h1 + (size_t)node * 64 + sub * 2) = o;
}

// ===== gather 2: out[r] (f32, width32) = C2s[r] + mean_k C2n[esrc[k]] =====
// 16 lanes per node, 16 nodes/block
__global__ __launch_bounds__(256) void k_gath2(const int* __restrict__ off,
                                               const int* __restrict__ esrc,
                                               const float* __restrict__ C2s,
                                               const unsigned short* __restrict__ C2n,
                                               float* __restrict__ out) {
    int node = blockIdx.x * 16 + (threadIdx.x >> 4);
    int sub  = threadIdx.x & 15;
    if (node >= NN) return;
    int beg = off[node], end = off[node + 1];
    float a0 = 0.f, a1 = 0.f;
    for (int k = beg; k < end; ++k) {
        int s = esrc[k];
        unsigned int v = *(const unsigned int*)(C2n + (size_t)s * 32 + sub * 2);
        a0 += b2f((unsigned short)(v & 0xFFFF));
        a1 += b2f((unsigned short)(v >> 16));
    }
    float inv = (end > beg) ? 1.0f / (float)(end - beg) : 0.f;
    const float2 sv = *(const float2*)(C2s + (size_t)node * 32 + sub * 2);
    float2 o;
    o.x = sv.x + a0 * inv;
    o.y = sv.y + a1 * inv;
    *(float2*)(out + (size_t)node * 32 + sub * 2) = o;
}

extern "C" void kernel_launch(void* const* d_in, const int* in_sizes, int n_in,
                              void* d_out, int out_size, void* d_ws, size_t ws_size,
                              hipStream_t stream) {
    const float* feat    = (const float*)d_in[0];
    const int*   src     = (const int*)d_in[1];
    const int*   dst     = (const int*)d_in[2];
    const float* Wself1  = (const float*)d_in[3];
    const float* Wneigh1 = (const float*)d_in[4];
    const float* b1      = (const float*)d_in[5];
    const float* Wself2  = (const float*)d_in[6];
    const float* Wneigh2 = (const float*)d_in[7];
    const float* b2      = (const float*)d_in[8];
    float* out = (float*)d_out;

    char* ws = (char*)d_ws;
    size_t offb = 0;
    auto alloc = [&](size_t bytes) -> void* {
        void* p = ws + offb;
        offb += (bytes + 255) & ~(size_t)255;
        return p;
    };
    int*            cnt  = (int*)alloc((size_t)NN * sizeof(int));
    int*            off  = (int*)alloc((size_t)(NN + 1) * sizeof(int));
    int*            bsum = (int*)alloc(128 * sizeof(int));
    int*            esrc = (int*)alloc((size_t)NE * sizeof(int));
    unsigned short* C1   = (unsigned short*)alloc((size_t)NN * 128 * 2);  // 25.6 MB
    unsigned short* h1   = (unsigned short*)alloc((size_t)NN * 64 * 2);   // 12.8 MB
    // C2 aliases C1 (C1 fully consumed by k_gath1 before k_mfma2 runs)
    float*          C2s  = (float*)C1;                                     // N*32 f32
    unsigned short* C2n  = (unsigned short*)((char*)C1 + (size_t)NN * 32 * sizeof(float));

    constexpr int NB = (NN + 1023) / 1024;  // 98

    // CSR by dst
    hipMemsetAsync(cnt, 0, (size_t)NN * sizeof(int), stream);
    k_hist<<<(NE + 255) / 256, 256, 0, stream>>>(dst, cnt, NE);
    k_scan1<<<NB, 256, 0, stream>>>(cnt, bsum, NN);
    k_scan2<<<1, 128, 0, stream>>>(bsum, NB);
    k_scan3<<<NB, 256, 0, stream>>>(cnt, bsum, off, NN);
    hipMemcpyAsync(cnt, off, (size_t)NN * sizeof(int), hipMemcpyDeviceToDevice, stream);
    k_pos<<<(NE + 255) / 256, 256, 0, stream>>>(src, dst, cnt, esrc, NE);

    // layer 1
    k_mfma1<<<(NN + 63) / 64, 256, 0, stream>>>(feat, Wself1, Wneigh1, b1, C1);
    k_gath1<<<(NN + 7) / 8, 256, 0, stream>>>(off, esrc, C1, h1);

    // layer 2
    k_mfma2<<<(NN + 63) / 64, 256, 0, stream>>>(h1, Wself2, Wneigh2, b2, C2s, C2n);
    k_gath2<<<(NN + 15) / 16, 256, 0, stream>>>(off, esrc, C2s, C2n, out);
}

// Round 4
// 190.051 us; speedup vs baseline: 9.5503x; 1.5612x over previous
//
#include <hip/hip_runtime.h>

constexpr int NN    = 100000;
constexpr int NE    = 1200000;
constexpr int D_IN  = 64;
constexpr int D_HID = 64;
constexpr int D_OUT = 32;

typedef float  f32x4 __attribute__((ext_vector_type(4)));
typedef short  s16x8 __attribute__((ext_vector_type(8)));

static __device__ __forceinline__ unsigned short f2b(float f) {
    unsigned int u = __float_as_uint(f);
    u = (u + 0x7FFFu + ((u >> 16) & 1u)) >> 16;   // RNE
    return (unsigned short)u;
}
static __device__ __forceinline__ float b2f(unsigned short h) {
    return __uint_as_float((unsigned int)h << 16);
}

// ========== CSR build: one returning-atomic pass (counts + ranks) ==========
__global__ __launch_bounds__(256) void k_rank(const int* __restrict__ dst,
                                              int* __restrict__ cnt,
                                              int* __restrict__ rank, int E4) {
    int i = blockIdx.x * 256 + threadIdx.x;
    if (i >= E4) return;
    const int4 d = ((const int4*)dst)[i];
    int4 r;
    r.x = atomicAdd(&cnt[d.x], 1);
    r.y = atomicAdd(&cnt[d.y], 1);
    r.z = atomicAdd(&cnt[d.z], 1);
    r.w = atomicAdd(&cnt[d.w], 1);
    ((int4*)rank)[i] = r;
}

__global__ __launch_bounds__(256) void k_scan1(const int* __restrict__ cnt,
                                               int* __restrict__ bsum, int n) {
    __shared__ int lds[256];
    int base = blockIdx.x * 1024;
    int t = threadIdx.x;
    int s = 0;
#pragma unroll
    for (int u = 0; u < 4; ++u) {
        int i = base + t * 4 + u;
        if (i < n) s += cnt[i];
    }
    lds[t] = s;
    __syncthreads();
    for (int w = 128; w > 0; w >>= 1) {
        if (t < w) lds[t] += lds[t + w];
        __syncthreads();
    }
    if (t == 0) bsum[blockIdx.x] = lds[0];
}

__global__ __launch_bounds__(128) void k_scan2(int* __restrict__ bsum, int nb) {
    __shared__ int lds[128];
    int t = threadIdx.x;
    lds[t] = (t < nb) ? bsum[t] : 0;
    __syncthreads();
    for (int d = 1; d < 128; d <<= 1) {
        int v = (t >= d) ? lds[t - d] : 0;
        __syncthreads();
        lds[t] += v;
        __syncthreads();
    }
    if (t < nb) bsum[t] = (t == 0) ? 0 : lds[t - 1];
}

__global__ __launch_bounds__(256) void k_scan3(const int* __restrict__ cnt,
                                               const int* __restrict__ bsum,
                                               int* __restrict__ off, int n) {
    __shared__ int lds[256];
    int base = blockIdx.x * 1024;
    int t = threadIdx.x;
    int v[4];
    int s = 0;
#pragma unroll
    for (int u = 0; u < 4; ++u) {
        int i = base + t * 4 + u;
        v[u] = (i < n) ? cnt[i] : 0;
        s += v[u];
    }
    lds[t] = s;
    __syncthreads();
    for (int d = 1; d < 256; d <<= 1) {
        int x = (t >= d) ? lds[t - d] : 0;
        __syncthreads();
        lds[t] += x;
        __syncthreads();
    }
    int excl = bsum[blockIdx.x] + ((t == 0) ? 0 : lds[t - 1]);
#pragma unroll
    for (int u = 0; u < 4; ++u) {
        int i = base + t * 4 + u;
        if (i < n) off[i] = excl;
        excl += v[u];
    }
    if (blockIdx.x == gridDim.x - 1 && t == 255) off[n] = excl;
}

__global__ __launch_bounds__(256) void k_place(const int* __restrict__ src,
                                               const int* __restrict__ dst,
                                               const int* __restrict__ rank,
                                               const int* __restrict__ off,
                                               int* __restrict__ esrc, int E4) {
    int i = blockIdx.x * 256 + threadIdx.x;
    if (i >= E4) return;
    const int4 s = ((const int4*)src)[i];
    const int4 d = ((const int4*)dst)[i];
    const int4 r = ((const int4*)rank)[i];
    esrc[off[d.x] + r.x] = s.x;
    esrc[off[d.y] + r.y] = s.y;
    esrc[off[d.z] + r.z] = s.z;
    esrc[off[d.w] + r.w] = s.w;
}

// ================= MFMA GEMM 1: C1[N x 128](bf16) = feat @ [Ws1|Wn1] (+b1 on cols<64) ====
__global__ __launch_bounds__(256) void k_mfma1(const float* __restrict__ feat,
                                               const float* __restrict__ Ws,
                                               const float* __restrict__ Wn,
                                               const float* __restrict__ b,
                                               unsigned short* __restrict__ C1) {
    __shared__ unsigned short Bl[16 * 64 * 8];  // [frag=ct*2+kt][lane][8] 16KB
    const int tid = threadIdx.x;
    for (int idx = tid; idx < 16 * 64; idx += 256) {
        int frag = idx >> 6, le = idx & 63;
        int ct = frag >> 1, kt = frag & 1;
        int col = ct * 16 + (le & 15);
        int kb  = kt * 32 + (le >> 4) * 8;
        unsigned short tmp[8];
#pragma unroll
        for (int j = 0; j < 8; ++j) {
            int k = kb + j;
            float w = (col < 64) ? Ws[k * 64 + col] : Wn[k * 64 + (col - 64)];
            tmp[j] = f2b(w);
        }
        uint4 pk;
        pk.x = (unsigned)tmp[0] | ((unsigned)tmp[1] << 16);
        pk.y = (unsigned)tmp[2] | ((unsigned)tmp[3] << 16);
        pk.z = (unsigned)tmp[4] | ((unsigned)tmp[5] << 16);
        pk.w = (unsigned)tmp[6] | ((unsigned)tmp[7] << 16);
        *(uint4*)(&Bl[idx * 8]) = pk;
    }
    __syncthreads();

    const int wave = tid >> 6, lane = tid & 63;
    const int r0 = blockIdx.x * 64 + wave * 16;

    s16x8 a[2];
#pragma unroll
    for (int kt = 0; kt < 2; ++kt) {
        int row = r0 + (lane & 15);
        if (row >= NN) row = NN - 1;
        int kb = kt * 32 + (lane >> 4) * 8;
        const float4 f0 = *(const float4*)(feat + (size_t)row * 64 + kb);
        const float4 f1 = *(const float4*)(feat + (size_t)row * 64 + kb + 4);
        a[kt][0] = (short)f2b(f0.x); a[kt][1] = (short)f2b(f0.y);
        a[kt][2] = (short)f2b(f0.z); a[kt][3] = (short)f2b(f0.w);
        a[kt][4] = (short)f2b(f1.x); a[kt][5] = (short)f2b(f1.y);
        a[kt][6] = (short)f2b(f1.z); a[kt][7] = (short)f2b(f1.w);
    }

    const s16x8* Bl8 = (const s16x8*)Bl;
#pragma unroll
    for (int ct = 0; ct < 8; ++ct) {
        f32x4 acc = {0.f, 0.f, 0.f, 0.f};
#pragma unroll
        for (int kt = 0; kt < 2; ++kt) {
            s16x8 bf = Bl8[(ct * 2 + kt) * 64 + lane];
            acc = __builtin_amdgcn_mfma_f32_16x16x32_bf16(a[kt], bf, acc, 0, 0, 0);
        }
        int c = ct * 16 + (lane & 15);
        float bias = (c < 64) ? b[c] : 0.f;
#pragma unroll
        for (int q = 0; q < 4; ++q) {
            int r = r0 + (lane >> 4) * 4 + q;
            if (r < NN) C1[(size_t)r * 128 + c] = f2b(acc[q] + bias);
        }
    }
}

// ===== MFMA GEMM 2: [C2s f32 | C2n bf16] (N x 32 each) = h1(bf16) @ [Ws2|Wn2] (+b2 on self)
__global__ __launch_bounds__(256) void k_mfma2(const unsigned short* __restrict__ h1,
                                               const float* __restrict__ Ws,
                                               const float* __restrict__ Wn,
                                               const float* __restrict__ b,
                                               float* __restrict__ C2s,
                                               unsigned short* __restrict__ C2n) {
    __shared__ unsigned short Bl[8 * 64 * 8];  // 8KB
    const int tid = threadIdx.x;
    for (int idx = tid; idx < 8 * 64; idx += 256) {
        int frag = idx >> 6, le = idx & 63;
        int ct = frag >> 1, kt = frag & 1;
        int col = ct * 16 + (le & 15);
        int kb  = kt * 32 + (le >> 4) * 8;
        unsigned short tmp[8];
#pragma unroll
        for (int j = 0; j < 8; ++j) {
            int k = kb + j;
            float w = (col < 32) ? Ws[k * 32 + col] : Wn[k * 32 + (col - 32)];
            tmp[j] = f2b(w);
        }
        uint4 pk;
        pk.x = (unsigned)tmp[0] | ((unsigned)tmp[1] << 16);
        pk.y = (unsigned)tmp[2] | ((unsigned)tmp[3] << 16);
        pk.z = (unsigned)tmp[4] | ((unsigned)tmp[5] << 16);
        pk.w = (unsigned)tmp[6] | ((unsigned)tmp[7] << 16);
        *(uint4*)(&Bl[idx * 8]) = pk;
    }
    __syncthreads();

    const int wave = tid >> 6, lane = tid & 63;
    const int r0 = blockIdx.x * 64 + wave * 16;

    s16x8 a[2];
#pragma unroll
    for (int kt = 0; kt < 2; ++kt) {
        int row = r0 + (lane & 15);
        if (row >= NN) row = NN - 1;
        int kb = kt * 32 + (lane >> 4) * 8;
        a[kt] = *(const s16x8*)(h1 + (size_t)row * 64 + kb);
    }

    const s16x8* Bl8 = (const s16x8*)Bl;
#pragma unroll
    for (int ct = 0; ct < 4; ++ct) {
        f32x4 acc = {0.f, 0.f, 0.f, 0.f};
#pragma unroll
        for (int kt = 0; kt < 2; ++kt) {
            s16x8 bf = Bl8[(ct * 2 + kt) * 64 + lane];
            acc = __builtin_amdgcn_mfma_f32_16x16x32_bf16(a[kt], bf, acc, 0, 0, 0);
        }
        int c = ct * 16 + (lane & 15);
#pragma unroll
        for (int q = 0; q < 4; ++q) {
            int r = r0 + (lane >> 4) * 4 + q;
            if (r < NN) {
                if (c < 32) C2s[(size_t)r * 32 + c] = acc[q] + b[c];
                else        C2n[(size_t)r * 32 + (c - 32)] = f2b(acc[q]);
            }
        }
    }
}

// ===== gather 1: h1[r] (bf16, width64) = C1self[r] + mean_k C1neigh[esrc[k]] =====
__global__ __launch_bounds__(256) void k_gath1(const int* __restrict__ off,
                                               const int* __restrict__ esrc,
                                               const unsigned short* __restrict__ C1,
                                               unsigned short* __restrict__ h1) {
    int node = blockIdx.x * 8 + (threadIdx.x >> 5);
    int sub  = threadIdx.x & 31;
    if (node >= NN) return;
    int beg = off[node], end = off[node + 1];
    float a0 = 0.f, a1 = 0.f, c0 = 0.f, c1 = 0.f;
    int k = beg;
    for (; k + 1 < end; k += 2) {
        int s0 = esrc[k], s1 = esrc[k + 1];
        unsigned int v0 = *(const unsigned int*)(C1 + (size_t)s0 * 128 + 64 + sub * 2);
        unsigned int v1 = *(const unsigned int*)(C1 + (size_t)s1 * 128 + 64 + sub * 2);
        a0 += b2f((unsigned short)(v0 & 0xFFFF));
        a1 += b2f((unsigned short)(v0 >> 16));
        c0 += b2f((unsigned short)(v1 & 0xFFFF));
        c1 += b2f((unsigned short)(v1 >> 16));
    }
    if (k < end) {
        int s = esrc[k];
        unsigned int v = *(const unsigned int*)(C1 + (size_t)s * 128 + 64 + sub * 2);
        a0 += b2f((unsigned short)(v & 0xFFFF));
        a1 += b2f((unsigned short)(v >> 16));
    }
    a0 += c0; a1 += c1;
    float inv = (end > beg) ? 1.0f / (float)(end - beg) : 0.f;
    unsigned int sv = *(const unsigned int*)(C1 + (size_t)node * 128 + sub * 2);
    float h0 = b2f((unsigned short)(sv & 0xFFFF)) + a0 * inv;
    float h1v = b2f((unsigned short)(sv >> 16)) + a1 * inv;
    unsigned int o = (unsigned int)f2b(h0) | ((unsigned int)f2b(h1v) << 16);
    *(unsigned int*)(h1 + (size_t)node * 64 + sub * 2) = o;
}

// ===== gather 2: out[r] (f32, width32) = C2s[r] + mean_k C2n[esrc[k]] =====
__global__ __launch_bounds__(256) void k_gath2(const int* __restrict__ off,
                                               const int* __restrict__ esrc,
                                               const float* __restrict__ C2s,
                                               const unsigned short* __restrict__ C2n,
                                               float* __restrict__ out) {
    int node = blockIdx.x * 16 + (threadIdx.x >> 4);
    int sub  = threadIdx.x & 15;
    if (node >= NN) return;
    int beg = off[node], end = off[node + 1];
    float a0 = 0.f, a1 = 0.f, c0 = 0.f, c1 = 0.f;
    int k = beg;
    for (; k + 1 < end; k += 2) {
        int s0 = esrc[k], s1 = esrc[k + 1];
        unsigned int v0 = *(const unsigned int*)(C2n + (size_t)s0 * 32 + sub * 2);
        unsigned int v1 = *(const unsigned int*)(C2n + (size_t)s1 * 32 + sub * 2);
        a0 += b2f((unsigned short)(v0 & 0xFFFF));
        a1 += b2f((unsigned short)(v0 >> 16));
        c0 += b2f((unsigned short)(v1 & 0xFFFF));
        c1 += b2f((unsigned short)(v1 >> 16));
    }
    if (k < end) {
        int s = esrc[k];
        unsigned int v = *(const unsigned int*)(C2n + (size_t)s * 32 + sub * 2);
        a0 += b2f((unsigned short)(v & 0xFFFF));
        a1 += b2f((unsigned short)(v >> 16));
    }
    a0 += c0; a1 += c1;
    float inv = (end > beg) ? 1.0f / (float)(end - beg) : 0.f;
    const float2 sv = *(const float2*)(C2s + (size_t)node * 32 + sub * 2);
    float2 o;
    o.x = sv.x + a0 * inv;
    o.y = sv.y + a1 * inv;
    *(float2*)(out + (size_t)node * 32 + sub * 2) = o;
}

extern "C" void kernel_launch(void* const* d_in, const int* in_sizes, int n_in,
                              void* d_out, int out_size, void* d_ws, size_t ws_size,
                              hipStream_t stream) {
    const float* feat    = (const float*)d_in[0];
    const int*   src     = (const int*)d_in[1];
    const int*   dst     = (const int*)d_in[2];
    const float* Wself1  = (const float*)d_in[3];
    const float* Wneigh1 = (const float*)d_in[4];
    const float* b1      = (const float*)d_in[5];
    const float* Wself2  = (const float*)d_in[6];
    const float* Wneigh2 = (const float*)d_in[7];
    const float* b2      = (const float*)d_in[8];
    float* out = (float*)d_out;

    char* ws = (char*)d_ws;
    size_t offb = 0;
    auto alloc = [&](size_t bytes) -> void* {
        void* p = ws + offb;
        offb += (bytes + 255) & ~(size_t)255;
        return p;
    };
    int*            cnt  = (int*)alloc((size_t)NN * sizeof(int));
    int*            off  = (int*)alloc((size_t)(NN + 1) * sizeof(int));
    int*            bsum = (int*)alloc(128 * sizeof(int));
    int*            rank = (int*)alloc((size_t)NE * sizeof(int));
    int*            esrc = (int*)alloc((size_t)NE * sizeof(int));
    unsigned short* C1   = (unsigned short*)alloc((size_t)NN * 128 * 2);  // 25.6 MB
    unsigned short* h1   = (unsigned short*)alloc((size_t)NN * 64 * 2);   // 12.8 MB
    float*          C2s  = (float*)C1;                                     // aliases C1
    unsigned short* C2n  = (unsigned short*)((char*)C1 + (size_t)NN * 32 * sizeof(float));

    constexpr int NB = (NN + 1023) / 1024;  // 98
    constexpr int E4 = NE / 4;              // 300000

    // CSR by dst: single returning-atomic pass -> counts + ranks
    hipMemsetAsync(cnt, 0, (size_t)NN * sizeof(int), stream);
    k_rank<<<(E4 + 255) / 256, 256, 0, stream>>>(dst, cnt, rank, E4);
    k_scan1<<<NB, 256, 0, stream>>>(cnt, bsum, NN);
    k_scan2<<<1, 128, 0, stream>>>(bsum, NB);
    k_scan3<<<NB, 256, 0, stream>>>(cnt, bsum, off, NN);
    k_place<<<(E4 + 255) / 256, 256, 0, stream>>>(src, dst, rank, off, esrc, E4);

    // layer 1
    k_mfma1<<<(NN + 63) / 64, 256, 0, stream>>>(feat, Wself1, Wneigh1, b1, C1);
    k_gath1<<<(NN + 7) / 8, 256, 0, stream>>>(off, esrc, C1, h1);

    // layer 2
    k_mfma2<<<(NN + 63) / 64, 256, 0, stream>>>(h1, Wself2, Wneigh2, b2, C2s, C2n);
    k_gath2<<<(NN + 15) / 16, 256, 0, stream>>>(off, esrc, C2s, C2n, out);
}

// Round 5
// 184.314 us; speedup vs baseline: 9.8475x; 1.0311x over previous
//
#include <hip/hip_runtime.h>

constexpr int NN    = 100000;
constexpr int NE    = 1200000;
constexpr int D_IN  = 64;
constexpr int D_HID = 64;
constexpr int D_OUT = 32;

typedef float  f32x4 __attribute__((ext_vector_type(4)));
typedef short  s16x8 __attribute__((ext_vector_type(8)));

static __device__ __forceinline__ unsigned short f2b(float f) {
    unsigned int u = __float_as_uint(f);
    u = (u + 0x7FFFu + ((u >> 16) & 1u)) >> 16;   // RNE
    return (unsigned short)u;
}
static __device__ __forceinline__ float b2f(unsigned short h) {
    return __uint_as_float((unsigned int)h << 16);
}

constexpr int E4  = NE / 4;                 // 300000
constexpr int NBR = (E4 + 255) / 256;       // 1172 rank blocks
constexpr int NBM = (NN + 63) / 64;         // 1563 mfma1 blocks
constexpr int NGRP = ((NBR + 2) / 3 > (NBM + 3) / 4) ? (NBR + 2) / 3 : (NBM + 3) / 4; // 391

// ========== merged: rank (returning atomics) + GEMM1, co-resident ==========
// rank: rank[e] = old count of dst[e];  mfma1: C1[N x 128](bf16) = feat @ [Ws|Wn] (+b on self)
__global__ __launch_bounds__(256) void k_rank_mfma1(const int* __restrict__ dst,
                                                    int* __restrict__ cnt,
                                                    int* __restrict__ rank,
                                                    const float* __restrict__ feat,
                                                    const float* __restrict__ Ws,
                                                    const float* __restrict__ Wn,
                                                    const float* __restrict__ b,
                                                    unsigned short* __restrict__ C1) {
    __shared__ unsigned short Bl[16 * 64 * 8];  // 16KB (mfma role only)
    const int grp = blockIdx.x / 7, rem = blockIdx.x % 7;
    const int tid = threadIdx.x;

    if (rem < 3) {  // ---- rank role ----
        int rid = grp * 3 + rem;
        if (rid >= NBR) return;
        int i = rid * 256 + tid;
        if (i >= E4) return;
        const int4 d = ((const int4*)dst)[i];
        int4 r;
        r.x = atomicAdd(&cnt[d.x], 1);
        r.y = atomicAdd(&cnt[d.y], 1);
        r.z = atomicAdd(&cnt[d.z], 1);
        r.w = atomicAdd(&cnt[d.w], 1);
        ((int4*)rank)[i] = r;
        return;
    }

    // ---- mfma1 role ----
    int mid = grp * 4 + (rem - 3);
    if (mid >= NBM) return;

    for (int idx = tid; idx < 16 * 64; idx += 256) {
        int frag = idx >> 6, le = idx & 63;
        int ct = frag >> 1, kt = frag & 1;
        int col = ct * 16 + (le & 15);
        int kb  = kt * 32 + (le >> 4) * 8;
        unsigned short tmp[8];
#pragma unroll
        for (int j = 0; j < 8; ++j) {
            int k = kb + j;
            float w = (col < 64) ? Ws[k * 64 + col] : Wn[k * 64 + (col - 64)];
            tmp[j] = f2b(w);
        }
        uint4 pk;
        pk.x = (unsigned)tmp[0] | ((unsigned)tmp[1] << 16);
        pk.y = (unsigned)tmp[2] | ((unsigned)tmp[3] << 16);
        pk.z = (unsigned)tmp[4] | ((unsigned)tmp[5] << 16);
        pk.w = (unsigned)tmp[6] | ((unsigned)tmp[7] << 16);
        *(uint4*)(&Bl[idx * 8]) = pk;
    }
    __syncthreads();

    const int wave = tid >> 6, lane = tid & 63;
    const int r0 = mid * 64 + wave * 16;

    s16x8 a[2];
#pragma unroll
    for (int kt = 0; kt < 2; ++kt) {
        int row = r0 + (lane & 15);
        if (row >= NN) row = NN - 1;
        int kb = kt * 32 + (lane >> 4) * 8;
        const float4 f0 = *(const float4*)(feat + (size_t)row * 64 + kb);
        const float4 f1 = *(const float4*)(feat + (size_t)row * 64 + kb + 4);
        a[kt][0] = (short)f2b(f0.x); a[kt][1] = (short)f2b(f0.y);
        a[kt][2] = (short)f2b(f0.z); a[kt][3] = (short)f2b(f0.w);
        a[kt][4] = (short)f2b(f1.x); a[kt][5] = (short)f2b(f1.y);
        a[kt][6] = (short)f2b(f1.z); a[kt][7] = (short)f2b(f1.w);
    }

    const s16x8* Bl8 = (const s16x8*)Bl;
#pragma unroll
    for (int ct = 0; ct < 8; ++ct) {
        f32x4 acc = {0.f, 0.f, 0.f, 0.f};
#pragma unroll
        for (int kt = 0; kt < 2; ++kt) {
            s16x8 bf = Bl8[(ct * 2 + kt) * 64 + lane];
            acc = __builtin_amdgcn_mfma_f32_16x16x32_bf16(a[kt], bf, acc, 0, 0, 0);
        }
        int c = ct * 16 + (lane & 15);
        float bias = (c < 64) ? b[c] : 0.f;
#pragma unroll
        for (int q = 0; q < 4; ++q) {
            int r = r0 + (lane >> 4) * 4 + q;
            if (r < NN) C1[(size_t)r * 128 + c] = f2b(acc[q] + bias);
        }
    }
}

// ================= scans =================
__global__ __launch_bounds__(256) void k_scan1(const int* __restrict__ cnt,
                                               int* __restrict__ bsum, int n) {
    __shared__ int lds[256];
    int base = blockIdx.x * 1024;
    int t = threadIdx.x;
    int s = 0;
#pragma unroll
    for (int u = 0; u < 4; ++u) {
        int i = base + t * 4 + u;
        if (i < n) s += cnt[i];
    }
    lds[t] = s;
    __syncthreads();
    for (int w = 128; w > 0; w >>= 1) {
        if (t < w) lds[t] += lds[t + w];
        __syncthreads();
    }
    if (t == 0) bsum[blockIdx.x] = lds[0];
}

__global__ __launch_bounds__(128) void k_scan2(int* __restrict__ bsum, int nb) {
    __shared__ int lds[128];
    int t = threadIdx.x;
    lds[t] = (t < nb) ? bsum[t] : 0;
    __syncthreads();
    for (int d = 1; d < 128; d <<= 1) {
        int v = (t >= d) ? lds[t - d] : 0;
        __syncthreads();
        lds[t] += v;
        __syncthreads();
    }
    if (t < nb) bsum[t] = (t == 0) ? 0 : lds[t - 1];
}

__global__ __launch_bounds__(256) void k_scan3(const int* __restrict__ cnt,
                                               const int* __restrict__ bsum,
                                               int* __restrict__ off, int n) {
    __shared__ int lds[256];
    int base = blockIdx.x * 1024;
    int t = threadIdx.x;
    int v[4];
    int s = 0;
#pragma unroll
    for (int u = 0; u < 4; ++u) {
        int i = base + t * 4 + u;
        v[u] = (i < n) ? cnt[i] : 0;
        s += v[u];
    }
    lds[t] = s;
    __syncthreads();
    for (int d = 1; d < 256; d <<= 1) {
        int x = (t >= d) ? lds[t - d] : 0;
        __syncthreads();
        lds[t] += x;
        __syncthreads();
    }
    int excl = bsum[blockIdx.x] + ((t == 0) ? 0 : lds[t - 1]);
#pragma unroll
    for (int u = 0; u < 4; ++u) {
        int i = base + t * 4 + u;
        if (i < n) off[i] = excl;
        excl += v[u];
    }
    if (blockIdx.x == gridDim.x - 1 && t == 255) off[n] = excl;
}

__global__ __launch_bounds__(256) void k_place(const int* __restrict__ src,
                                               const int* __restrict__ dst,
                                               const int* __restrict__ rank,
                                               const int* __restrict__ off,
                                               int* __restrict__ esrc, int n4) {
    int i = blockIdx.x * 256 + threadIdx.x;
    if (i >= n4) return;
    const int4 s = ((const int4*)src)[i];
    const int4 d = ((const int4*)dst)[i];
    const int4 r = ((const int4*)rank)[i];
    esrc[off[d.x] + r.x] = s.x;
    esrc[off[d.y] + r.y] = s.y;
    esrc[off[d.z] + r.z] = s.z;
    esrc[off[d.w] + r.w] = s.w;
}

// ===== fused: gather-mean layer1 -> LDS h1 tile (swizzled) -> GEMM2 =====
// out per block: 64 nodes. C2s (f32, self+b2), C2n (bf16, neighbor-transform)
__global__ __launch_bounds__(256) void k_gath1_mfma2(const int* __restrict__ off,
                                                     const int* __restrict__ esrc,
                                                     const unsigned short* __restrict__ C1,
                                                     const float* __restrict__ Ws,
                                                     const float* __restrict__ Wn,
                                                     const float* __restrict__ b,
                                                     float* __restrict__ C2s,
                                                     unsigned short* __restrict__ C2n) {
    __shared__ unsigned short Bl[8 * 64 * 8];  // 8KB weight frags
    __shared__ unsigned short Hl[64 * 64];     // 8KB h1 tile, XOR-swizzled rows
    const int tid = threadIdx.x;

    // stage B2 fragments (no sync needed until after gather phase)
    for (int idx = tid; idx < 8 * 64; idx += 256) {
        int frag = idx >> 6, le = idx & 63;
        int ct = frag >> 1, kt = frag & 1;
        int col = ct * 16 + (le & 15);
        int kb  = kt * 32 + (le >> 4) * 8;
        unsigned short tmp[8];
#pragma unroll
        for (int j = 0; j < 8; ++j) {
            int k = kb + j;
            float w = (col < 32) ? Ws[k * 32 + col] : Wn[k * 32 + (col - 32)];
            tmp[j] = f2b(w);
        }
        uint4 pk;
        pk.x = (unsigned)tmp[0] | ((unsigned)tmp[1] << 16);
        pk.y = (unsigned)tmp[2] | ((unsigned)tmp[3] << 16);
        pk.z = (unsigned)tmp[4] | ((unsigned)tmp[5] << 16);
        pk.w = (unsigned)tmp[6] | ((unsigned)tmp[7] << 16);
        *(uint4*)(&Bl[idx * 8]) = pk;
    }

    // ---- gather phase: h1[rloc] = C1self + mean(C1neigh) -> LDS (bf16x2 per lane) ----
    const int base = blockIdx.x * 64;
    const int sub = tid & 31;
#pragma unroll 1
    for (int g = 0; g < 8; ++g) {
        int rloc = g * 8 + (tid >> 5);
        int node = base + rloc;
        if (node < NN) {
            int beg = off[node], end = off[node + 1];
            float a0 = 0.f, a1 = 0.f, c0 = 0.f, c1 = 0.f;
            int k = beg;
            for (; k + 1 < end; k += 2) {
                int s0 = esrc[k], s1 = esrc[k + 1];
                unsigned int v0 = *(const unsigned int*)(C1 + (size_t)s0 * 128 + 64 + sub * 2);
                unsigned int v1 = *(const unsigned int*)(C1 + (size_t)s1 * 128 + 64 + sub * 2);
                a0 += b2f((unsigned short)(v0 & 0xFFFF));
                a1 += b2f((unsigned short)(v0 >> 16));
                c0 += b2f((unsigned short)(v1 & 0xFFFF));
                c1 += b2f((unsigned short)(v1 >> 16));
            }
            if (k < end) {
                int s = esrc[k];
                unsigned int v = *(const unsigned int*)(C1 + (size_t)s * 128 + 64 + sub * 2);
                a0 += b2f((unsigned short)(v & 0xFFFF));
                a1 += b2f((unsigned short)(v >> 16));
            }
            a0 += c0; a1 += c1;
            float inv = (end > beg) ? 1.0f / (float)(end - beg) : 0.f;
            unsigned int sv = *(const unsigned int*)(C1 + (size_t)node * 128 + sub * 2);
            float h0 = b2f((unsigned short)(sv & 0xFFFF)) + a0 * inv;
            float h1v = b2f((unsigned short)(sv >> 16)) + a1 * inv;
            unsigned int o = (unsigned int)f2b(h0) | ((unsigned int)f2b(h1v) << 16);
            int boff = (rloc * 128 + sub * 4) ^ ((rloc & 7) << 4);
            *(unsigned int*)((char*)Hl + boff) = o;
        }
    }
    __syncthreads();

    // ---- mfma2 phase: rows from swizzled LDS ----
    const int wave = tid >> 6, lane = tid & 63;
    const int rl = wave * 16 + (lane & 15);

    s16x8 a[2];
#pragma unroll
    for (int kt = 0; kt < 2; ++kt) {
        int boff = rl * 128 + kt * 64 + (lane >> 4) * 16;
        a[kt] = *(const s16x8*)((const char*)Hl + (boff ^ ((rl & 7) << 4)));
    }

    const s16x8* Bl8 = (const s16x8*)Bl;
#pragma unroll
    for (int ct = 0; ct < 4; ++ct) {
        f32x4 acc = {0.f, 0.f, 0.f, 0.f};
#pragma unroll
        for (int kt = 0; kt < 2; ++kt) {
            s16x8 bf = Bl8[(ct * 2 + kt) * 64 + lane];
            acc = __builtin_amdgcn_mfma_f32_16x16x32_bf16(a[kt], bf, acc, 0, 0, 0);
        }
        int c = ct * 16 + (lane & 15);
#pragma unroll
        for (int q = 0; q < 4; ++q) {
            int r = blockIdx.x * 64 + wave * 16 + (lane >> 4) * 4 + q;
            if (r < NN) {
                if (c < 32) C2s[(size_t)r * 32 + c] = acc[q] + b[c];
                else        C2n[(size_t)r * 32 + (c - 32)] = f2b(acc[q]);
            }
        }
    }
}

// ===== gather 2: out[r] (f32, width32) = C2s[r] + mean_k C2n[esrc[k]] =====
__global__ __launch_bounds__(256) void k_gath2(const int* __restrict__ off,
                                               const int* __restrict__ esrc,
                                               const float* __restrict__ C2s,
                                               const unsigned short* __restrict__ C2n,
                                               float* __restrict__ out) {
    int node = blockIdx.x * 16 + (threadIdx.x >> 4);
    int sub  = threadIdx.x & 15;
    if (node >= NN) return;
    int beg = off[node], end = off[node + 1];
    float a0 = 0.f, a1 = 0.f, c0 = 0.f, c1 = 0.f;
    int k = beg;
    for (; k + 1 < end; k += 2) {
        int s0 = esrc[k], s1 = esrc[k + 1];
        unsigned int v0 = *(const unsigned int*)(C2n + (size_t)s0 * 32 + sub * 2);
        unsigned int v1 = *(const unsigned int*)(C2n + (size_t)s1 * 32 + sub * 2);
        a0 += b2f((unsigned short)(v0 & 0xFFFF));
        a1 += b2f((unsigned short)(v0 >> 16));
        c0 += b2f((unsigned short)(v1 & 0xFFFF));
        c1 += b2f((unsigned short)(v1 >> 16));
    }
    if (k < end) {
        int s = esrc[k];
        unsigned int v = *(const unsigned int*)(C2n + (size_t)s * 32 + sub * 2);
        a0 += b2f((unsigned short)(v & 0xFFFF));
        a1 += b2f((unsigned short)(v >> 16));
    }
    a0 += c0; a1 += c1;
    float inv = (end > beg) ? 1.0f / (float)(end - beg) : 0.f;
    const float2 sv = *(const float2*)(C2s + (size_t)node * 32 + sub * 2);
    float2 o;
    o.x = sv.x + a0 * inv;
    o.y = sv.y + a1 * inv;
    *(float2*)(out + (size_t)node * 32 + sub * 2) = o;
}

extern "C" void kernel_launch(void* const* d_in, const int* in_sizes, int n_in,
                              void* d_out, int out_size, void* d_ws, size_t ws_size,
                              hipStream_t stream) {
    const float* feat    = (const float*)d_in[0];
    const int*   src     = (const int*)d_in[1];
    const int*   dst     = (const int*)d_in[2];
    const float* Wself1  = (const float*)d_in[3];
    const float* Wneigh1 = (const float*)d_in[4];
    const float* b1      = (const float*)d_in[5];
    const float* Wself2  = (const float*)d_in[6];
    const float* Wneigh2 = (const float*)d_in[7];
    const float* b2      = (const float*)d_in[8];
    float* out = (float*)d_out;

    char* ws = (char*)d_ws;
    size_t offb = 0;
    auto alloc = [&](size_t bytes) -> void* {
        void* p = ws + offb;
        offb += (bytes + 255) & ~(size_t)255;
        return p;
    };
    int*            cnt  = (int*)alloc((size_t)NN * sizeof(int));
    int*            off  = (int*)alloc((size_t)(NN + 1) * sizeof(int));
    int*            bsum = (int*)alloc(128 * sizeof(int));
    int*            rank = (int*)alloc((size_t)NE * sizeof(int));
    int*            esrc = (int*)alloc((size_t)NE * sizeof(int));
    unsigned short* C1   = (unsigned short*)alloc((size_t)NN * 128 * 2);      // 25.6 MB
    float*          C2s  = (float*)alloc((size_t)NN * 32 * sizeof(float));    // 12.8 MB
    unsigned short* C2n  = (unsigned short*)alloc((size_t)NN * 32 * 2);       // 6.4 MB

    constexpr int NB = (NN + 1023) / 1024;  // 98

    // rank atomics + GEMM1 co-scheduled in one dispatch
    hipMemsetAsync(cnt, 0, (size_t)NN * sizeof(int), stream);
    k_rank_mfma1<<<NGRP * 7, 256, 0, stream>>>(dst, cnt, rank, feat, Wself1, Wneigh1, b1, C1);

    // offsets + placement
    k_scan1<<<NB, 256, 0, stream>>>(cnt, bsum, NN);
    k_scan2<<<1, 128, 0, stream>>>(bsum, NB);
    k_scan3<<<NB, 256, 0, stream>>>(cnt, bsum, off, NN);
    k_place<<<(E4 + 255) / 256, 256, 0, stream>>>(src, dst, rank, off, esrc, E4);

    // layer-1 gather + layer-2 GEMM fused; then layer-2 gather
    k_gath1_mfma2<<<(NN + 63) / 64, 256, 0, stream>>>(off, esrc, C1, Wself2, Wneigh2, b2, C2s, C2n);
    k_gath2<<<(NN + 15) / 16, 256, 0, stream>>>(off, esrc, C2s, C2n, out);
}

// Round 6
// 141.545 us; speedup vs baseline: 12.8230x; 1.3022x over previous
//
#include <hip/hip_runtime.h>

constexpr int NN    = 100000;
constexpr int NE    = 1200000;

constexpr int NBUK = 196;                 // coarse bucket = dst >> 9
constexpr int PB   = 256;                 // pass-1 blocks
constexpr int EPB  = (NE + PB - 1) / PB;  // 4688 edges / p1 block
constexpr int MAT  = NBUK * PB;           // 50176
constexpr int NBM  = (NN + 63) / 64;      // 1563 mfma1 blocks

typedef float  f32x4 __attribute__((ext_vector_type(4)));
typedef short  s16x8 __attribute__((ext_vector_type(8)));

static __device__ __forceinline__ unsigned short f2b(float f) {
    unsigned int u = __float_as_uint(f);
    u = (u + 0x7FFFu + ((u >> 16) & 1u)) >> 16;   // RNE
    return (unsigned short)u;
}
static __device__ __forceinline__ float b2f(unsigned short h) {
    return __uint_as_float((unsigned int)h << 16);
}

// ========== pass 1: per-block histogram over 196 coarse buckets ==========
__global__ __launch_bounds__(256) void k_p1hist(const int* __restrict__ dst,
                                                int* __restrict__ mat) {
    __shared__ int h[NBUK];
    const int t = threadIdx.x, blk = blockIdx.x;
    for (int i = t; i < NBUK; i += 256) h[i] = 0;
    __syncthreads();
    int beg = blk * EPB, end = beg + EPB;
    if (end > NE) end = NE;
    for (int i = beg + t; i < end; i += 256)
        atomicAdd(&h[dst[i] >> 9], 1);
    __syncthreads();
    for (int b = t; b < NBUK; b += 256) mat[b * PB + blk] = h[b];
}

// ================= generic scans (reused for the 50176-entry matrix) =========
__global__ __launch_bounds__(256) void k_scan1(const int* __restrict__ cnt,
                                               int* __restrict__ bsum, int n) {
    __shared__ int lds[256];
    int base = blockIdx.x * 1024;
    int t = threadIdx.x;
    int s = 0;
#pragma unroll
    for (int u = 0; u < 4; ++u) {
        int i = base + t * 4 + u;
        if (i < n) s += cnt[i];
    }
    lds[t] = s;
    __syncthreads();
    for (int w = 128; w > 0; w >>= 1) {
        if (t < w) lds[t] += lds[t + w];
        __syncthreads();
    }
    if (t == 0) bsum[blockIdx.x] = lds[0];
}

__global__ __launch_bounds__(128) void k_scan2(int* __restrict__ bsum, int nb) {
    __shared__ int lds[128];
    int t = threadIdx.x;
    lds[t] = (t < nb) ? bsum[t] : 0;
    __syncthreads();
    for (int d = 1; d < 128; d <<= 1) {
        int v = (t >= d) ? lds[t - d] : 0;
        __syncthreads();
        lds[t] += v;
        __syncthreads();
    }
    if (t < nb) bsum[t] = (t == 0) ? 0 : lds[t - 1];
}

__global__ __launch_bounds__(256) void k_scan3(const int* __restrict__ cnt,
                                               const int* __restrict__ bsum,
                                               int* __restrict__ off, int n) {
    __shared__ int lds[256];
    int base = blockIdx.x * 1024;
    int t = threadIdx.x;
    int v[4];
    int s = 0;
#pragma unroll
    for (int u = 0; u < 4; ++u) {
        int i = base + t * 4 + u;
        v[u] = (i < n) ? cnt[i] : 0;
        s += v[u];
    }
    lds[t] = s;
    __syncthreads();
    for (int d = 1; d < 256; d <<= 1) {
        int x = (t >= d) ? lds[t - d] : 0;
        __syncthreads();
        lds[t] += x;
        __syncthreads();
    }
    int excl = bsum[blockIdx.x] + ((t == 0) ? 0 : lds[t - 1]);
#pragma unroll
    for (int u = 0; u < 4; ++u) {
        int i = base + t * 4 + u;
        if (i < n) off[i] = excl;
        excl += v[u];
    }
    if (blockIdx.x == gridDim.x - 1 && t == 255) off[n] = excl;
}

// ========== pass 1 placement: packed (src | dlocal<<17) into reserved runs ====
__global__ __launch_bounds__(256) void k_p1place(const int* __restrict__ src,
                                                 const int* __restrict__ dst,
                                                 const int* __restrict__ matX,
                                                 unsigned int* __restrict__ P) {
    __shared__ int cur[NBUK];
    const int t = threadIdx.x, blk = blockIdx.x;
    for (int b = t; b < NBUK; b += 256) cur[b] = matX[b * PB + blk];
    __syncthreads();
    int beg = blk * EPB, end = beg + EPB;
    if (end > NE) end = NE;
    for (int i = beg + t; i < end; i += 256) {
        int d = dst[i], s = src[i];
        int pos = atomicAdd(&cur[d >> 9], 1);
        P[pos] = (unsigned)s | ((unsigned)(d & 511) << 17);
    }
}

// ========== merged: pass-2 LDS counting sort (blocks 0..195)  +  GEMM1 ========
// sort: per bucket, sort ~6.1K edges by local dst; emit esrc (coalesced) + off
// mfma1: C1[N x 128](bf16) = feat @ [Ws|Wn] (+b on self cols)
__global__ __launch_bounds__(256) void k_sort2_mfma1(const unsigned int* __restrict__ P,
                                                     const int* __restrict__ matX,
                                                     int* __restrict__ esrc,
                                                     int* __restrict__ off,
                                                     const float* __restrict__ feat,
                                                     const float* __restrict__ Ws,
                                                     const float* __restrict__ Wn,
                                                     const float* __restrict__ b,
                                                     unsigned short* __restrict__ C1) {
    __shared__ char smem[16384];
    const int tid = threadIdx.x;

    if (blockIdx.x < NBUK) {
        // ---- sort role ----
        const int bb = blockIdx.x;
        int* cnt = (int*)smem;            // [512] counts, later cursor
        int* sA  = (int*)(smem + 2048);   // [512]
        int* sB  = (int*)(smem + 4096);   // [512]
        const int beg = matX[bb * PB];
        const int end = matX[(bb + 1) * PB];

        for (int i = tid; i < 512; i += 256) cnt[i] = 0;
        __syncthreads();
        for (int i = beg + tid; i < end; i += 256)
            atomicAdd(&cnt[P[i] >> 17], 1);
        __syncthreads();
        for (int i = tid; i < 512; i += 256) sA[i] = cnt[i];
        __syncthreads();
        int* pin = sA; int* pout = sB;
        for (int d = 1; d < 512; d <<= 1) {
            for (int i = tid; i < 512; i += 256)
                pout[i] = pin[i] + (i >= d ? pin[i - d] : 0);
            __syncthreads();
            int* tmp = pin; pin = pout; pout = tmp;
        }
        // pin = inclusive scan; exclusive(i) = i ? pin[i-1] : 0
        const int nodes = (bb == NBUK - 1) ? (NN - (NBUK - 1) * 512) : 512;
        for (int i = tid; i < 512; i += 256) {
            int ex = i ? pin[i - 1] : 0;
            cnt[i] = ex;  // cursor
            if (i < nodes) off[bb * 512 + i] = beg + ex;
        }
        if (bb == NBUK - 1 && tid == 0) off[NN] = NE;
        __syncthreads();
        for (int i = beg + tid; i < end; i += 256) {
            unsigned v = P[i];
            int dl = (int)(v >> 17);
            int pos = atomicAdd(&cnt[dl], 1);
            esrc[beg + pos] = (int)(v & 0x1FFFFu);
        }
        return;
    }

    // ---- mfma1 role ----
    unsigned short* Bl = (unsigned short*)smem;  // [16*64*8] 16KB
    const int mid = blockIdx.x - NBUK;

    for (int idx = tid; idx < 16 * 64; idx += 256) {
        int frag = idx >> 6, le = idx & 63;
        int ct = frag >> 1, kt = frag & 1;
        int col = ct * 16 + (le & 15);
        int kb  = kt * 32 + (le >> 4) * 8;
        unsigned short tmp[8];
#pragma unroll
        for (int j = 0; j < 8; ++j) {
            int k = kb + j;
            float w = (col < 64) ? Ws[k * 64 + col] : Wn[k * 64 + (col - 64)];
            tmp[j] = f2b(w);
        }
        uint4 pk;
        pk.x = (unsigned)tmp[0] | ((unsigned)tmp[1] << 16);
        pk.y = (unsigned)tmp[2] | ((unsigned)tmp[3] << 16);
        pk.z = (unsigned)tmp[4] | ((unsigned)tmp[5] << 16);
        pk.w = (unsigned)tmp[6] | ((unsigned)tmp[7] << 16);
        *(uint4*)(&Bl[idx * 8]) = pk;
    }
    __syncthreads();

    const int wave = tid >> 6, lane = tid & 63;
    const int r0 = mid * 64 + wave * 16;

    s16x8 a[2];
#pragma unroll
    for (int kt = 0; kt < 2; ++kt) {
        int row = r0 + (lane & 15);
        if (row >= NN) row = NN - 1;
        int kb = kt * 32 + (lane >> 4) * 8;
        const float4 f0 = *(const float4*)(feat + (size_t)row * 64 + kb);
        const float4 f1 = *(const float4*)(feat + (size_t)row * 64 + kb + 4);
        a[kt][0] = (short)f2b(f0.x); a[kt][1] = (short)f2b(f0.y);
        a[kt][2] = (short)f2b(f0.z); a[kt][3] = (short)f2b(f0.w);
        a[kt][4] = (short)f2b(f1.x); a[kt][5] = (short)f2b(f1.y);
        a[kt][6] = (short)f2b(f1.z); a[kt][7] = (short)f2b(f1.w);
    }

    const s16x8* Bl8 = (const s16x8*)Bl;
#pragma unroll
    for (int ct = 0; ct < 8; ++ct) {
        f32x4 acc = {0.f, 0.f, 0.f, 0.f};
#pragma unroll
        for (int kt = 0; kt < 2; ++kt) {
            s16x8 bf = Bl8[(ct * 2 + kt) * 64 + lane];
            acc = __builtin_amdgcn_mfma_f32_16x16x32_bf16(a[kt], bf, acc, 0, 0, 0);
        }
        int c = ct * 16 + (lane & 15);
        float bias = (c < 64) ? b[c] : 0.f;
#pragma unroll
        for (int q = 0; q < 4; ++q) {
            int r = r0 + (lane >> 4) * 4 + q;
            if (r < NN) C1[(size_t)r * 128 + c] = f2b(acc[q] + bias);
        }
    }
}

// ===== fused: gather-mean layer1 -> LDS h1 tile (swizzled) -> GEMM2 =====
__global__ __launch_bounds__(256) void k_gath1_mfma2(const int* __restrict__ off,
                                                     const int* __restrict__ esrc,
                                                     const unsigned short* __restrict__ C1,
                                                     const float* __restrict__ Ws,
                                                     const float* __restrict__ Wn,
                                                     const float* __restrict__ b,
                                                     float* __restrict__ C2s,
                                                     unsigned short* __restrict__ C2n) {
    __shared__ unsigned short Bl[8 * 64 * 8];  // 8KB weight frags
    __shared__ unsigned short Hl[64 * 64];     // 8KB h1 tile, XOR-swizzled rows
    const int tid = threadIdx.x;

    for (int idx = tid; idx < 8 * 64; idx += 256) {
        int frag = idx >> 6, le = idx & 63;
        int ct = frag >> 1, kt = frag & 1;
        int col = ct * 16 + (le & 15);
        int kb  = kt * 32 + (le >> 4) * 8;
        unsigned short tmp[8];
#pragma unroll
        for (int j = 0; j < 8; ++j) {
            int k = kb + j;
            float w = (col < 32) ? Ws[k * 32 + col] : Wn[k * 32 + (col - 32)];
            tmp[j] = f2b(w);
        }
        uint4 pk;
        pk.x = (unsigned)tmp[0] | ((unsigned)tmp[1] << 16);
        pk.y = (unsigned)tmp[2] | ((unsigned)tmp[3] << 16);
        pk.z = (unsigned)tmp[4] | ((unsigned)tmp[5] << 16);
        pk.w = (unsigned)tmp[6] | ((unsigned)tmp[7] << 16);
        *(uint4*)(&Bl[idx * 8]) = pk;
    }

    const int base = blockIdx.x * 64;
    const int sub = tid & 31;
#pragma unroll 1
    for (int g = 0; g < 8; ++g) {
        int rloc = g * 8 + (tid >> 5);
        int node = base + rloc;
        if (node < NN) {
            int beg = off[node], end = off[node + 1];
            float a0 = 0.f, a1 = 0.f, c0 = 0.f, c1 = 0.f;
            int k = beg;
            for (; k + 1 < end; k += 2) {
                int s0 = esrc[k], s1 = esrc[k + 1];
                unsigned int v0 = *(const unsigned int*)(C1 + (size_t)s0 * 128 + 64 + sub * 2);
                unsigned int v1 = *(const unsigned int*)(C1 + (size_t)s1 * 128 + 64 + sub * 2);
                a0 += b2f((unsigned short)(v0 & 0xFFFF));
                a1 += b2f((unsigned short)(v0 >> 16));
                c0 += b2f((unsigned short)(v1 & 0xFFFF));
                c1 += b2f((unsigned short)(v1 >> 16));
            }
            if (k < end) {
                int s = esrc[k];
                unsigned int v = *(const unsigned int*)(C1 + (size_t)s * 128 + 64 + sub * 2);
                a0 += b2f((unsigned short)(v & 0xFFFF));
                a1 += b2f((unsigned short)(v >> 16));
            }
            a0 += c0; a1 += c1;
            float inv = (end > beg) ? 1.0f / (float)(end - beg) : 0.f;
            unsigned int sv = *(const unsigned int*)(C1 + (size_t)node * 128 + sub * 2);
            float h0 = b2f((unsigned short)(sv & 0xFFFF)) + a0 * inv;
            float h1v = b2f((unsigned short)(sv >> 16)) + a1 * inv;
            unsigned int o = (unsigned int)f2b(h0) | ((unsigned int)f2b(h1v) << 16);
            int boff = (rloc * 128 + sub * 4) ^ ((rloc & 7) << 4);
            *(unsigned int*)((char*)Hl + boff) = o;
        }
    }
    __syncthreads();

    const int wave = tid >> 6, lane = tid & 63;
    const int rl = wave * 16 + (lane & 15);

    s16x8 a[2];
#pragma unroll
    for (int kt = 0; kt < 2; ++kt) {
        int boff = rl * 128 + kt * 64 + (lane >> 4) * 16;
        a[kt] = *(const s16x8*)((const char*)Hl + (boff ^ ((rl & 7) << 4)));
    }

    const s16x8* Bl8 = (const s16x8*)Bl;
#pragma unroll
    for (int ct = 0; ct < 4; ++ct) {
        f32x4 acc = {0.f, 0.f, 0.f, 0.f};
#pragma unroll
        for (int kt = 0; kt < 2; ++kt) {
            s16x8 bf = Bl8[(ct * 2 + kt) * 64 + lane];
            acc = __builtin_amdgcn_mfma_f32_16x16x32_bf16(a[kt], bf, acc, 0, 0, 0);
        }
        int c = ct * 16 + (lane & 15);
#pragma unroll
        for (int q = 0; q < 4; ++q) {
            int r = blockIdx.x * 64 + wave * 16 + (lane >> 4) * 4 + q;
            if (r < NN) {
                if (c < 32) C2s[(size_t)r * 32 + c] = acc[q] + b[c];
                else        C2n[(size_t)r * 32 + (c - 32)] = f2b(acc[q]);
            }
        }
    }
}

// ===== gather 2: out[r] (f32, width32) = C2s[r] + mean_k C2n[esrc[k]] =====
__global__ __launch_bounds__(256) void k_gath2(const int* __restrict__ off,
                                               const int* __restrict__ esrc,
                                               const float* __restrict__ C2s,
                                               const unsigned short* __restrict__ C2n,
                                               float* __restrict__ out) {
    int node = blockIdx.x * 16 + (threadIdx.x >> 4);
    int sub  = threadIdx.x & 15;
    if (node >= NN) return;
    int beg = off[node], end = off[node + 1];
    float a0 = 0.f, a1 = 0.f, c0 = 0.f, c1 = 0.f;
    int k = beg;
    for (; k + 1 < end; k += 2) {
        int s0 = esrc[k], s1 = esrc[k + 1];
        unsigned int v0 = *(const unsigned int*)(C2n + (size_t)s0 * 32 + sub * 2);
        unsigned int v1 = *(const unsigned int*)(C2n + (size_t)s1 * 32 + sub * 2);
        a0 += b2f((unsigned short)(v0 & 0xFFFF));
        a1 += b2f((unsigned short)(v0 >> 16));
        c0 += b2f((unsigned short)(v1 & 0xFFFF));
        c1 += b2f((unsigned short)(v1 >> 16));
    }
    if (k < end) {
        int s = esrc[k];
        unsigned int v = *(const unsigned int*)(C2n + (size_t)s * 32 + sub * 2);
        a0 += b2f((unsigned short)(v & 0xFFFF));
        a1 += b2f((unsigned short)(v >> 16));
    }
    a0 += c0; a1 += c1;
    float inv = (end > beg) ? 1.0f / (float)(end - beg) : 0.f;
    const float2 sv = *(const float2*)(C2s + (size_t)node * 32 + sub * 2);
    float2 o;
    o.x = sv.x + a0 * inv;
    o.y = sv.y + a1 * inv;
    *(float2*)(out + (size_t)node * 32 + sub * 2) = o;
}

extern "C" void kernel_launch(void* const* d_in, const int* in_sizes, int n_in,
                              void* d_out, int out_size, void* d_ws, size_t ws_size,
                              hipStream_t stream) {
    const float* feat    = (const float*)d_in[0];
    const int*   src     = (const int*)d_in[1];
    const int*   dst     = (const int*)d_in[2];
    const float* Wself1  = (const float*)d_in[3];
    const float* Wneigh1 = (const float*)d_in[4];
    const float* b1      = (const float*)d_in[5];
    const float* Wself2  = (const float*)d_in[6];
    const float* Wneigh2 = (const float*)d_in[7];
    const float* b2      = (const float*)d_in[8];
    float* out = (float*)d_out;

    char* ws = (char*)d_ws;
    size_t offb = 0;
    auto alloc = [&](size_t bytes) -> void* {
        void* p = ws + offb;
        offb += (bytes + 255) & ~(size_t)255;
        return p;
    };
    int*            mat  = (int*)alloc((size_t)MAT * sizeof(int));            // 200 KB
    int*            matX = (int*)alloc((size_t)(MAT + 1) * sizeof(int));      // 200 KB
    int*            bsum = (int*)alloc(128 * sizeof(int));
    unsigned int*   P    = (unsigned int*)alloc((size_t)NE * sizeof(int));    // 4.8 MB
    int*            esrc = (int*)alloc((size_t)NE * sizeof(int));             // 4.8 MB
    int*            off  = (int*)alloc((size_t)(NN + 1) * sizeof(int));
    unsigned short* C1   = (unsigned short*)alloc((size_t)NN * 128 * 2);      // 25.6 MB
    float*          C2s  = (float*)alloc((size_t)NN * 32 * sizeof(float));    // 12.8 MB
    unsigned short* C2n  = (unsigned short*)alloc((size_t)NN * 32 * 2);       // 6.4 MB

    // ---- CSR build: two-pass LDS counting sort (no global atomics) ----
    k_p1hist<<<PB, 256, 0, stream>>>(dst, mat);
    k_scan1<<<MAT / 1024, 256, 0, stream>>>(mat, bsum, MAT);          // 49 blocks
    k_scan2<<<1, 128, 0, stream>>>(bsum, MAT / 1024);
    k_scan3<<<MAT / 1024, 256, 0, stream>>>(mat, bsum, matX, MAT);
    k_p1place<<<PB, 256, 0, stream>>>(src, dst, matX, P);

    // ---- pass-2 sort (196 blocks) + layer-1 GEMM (1563 blocks), one dispatch ----
    k_sort2_mfma1<<<NBUK + NBM, 256, 0, stream>>>(P, matX, esrc, off,
                                                  feat, Wself1, Wneigh1, b1, C1);

    // ---- layer-1 gather + layer-2 GEMM fused; then layer-2 gather ----
    k_gath1_mfma2<<<(NN + 63) / 64, 256, 0, stream>>>(off, esrc, C1, Wself2, Wneigh2, b2, C2s, C2n);
    k_gath2<<<(NN + 15) / 16, 256, 0, stream>>>(off, esrc, C2s, C2n, out);
}

// Round 7
// 109.780 us; speedup vs baseline: 16.5334x; 1.2894x over previous
//
#include <hip/hip_runtime.h>

constexpr int NN    = 100000;
constexpr int NE    = 1200000;

constexpr int NBUK = 196;                 // coarse bucket = dst >> 9
constexpr int PB   = 256;                 // pass-1 blocks
constexpr int EPB  = (NE + PB - 1) / PB;  // 4688 edges / p1 block
constexpr int MAT  = NBUK * PB;           // 50176
constexpr int NBM  = (NN + 63) / 64;      // 1563 mfma1 blocks

typedef float  f32x4 __attribute__((ext_vector_type(4)));
typedef short  s16x8 __attribute__((ext_vector_type(8)));

static __device__ __forceinline__ unsigned short f2b(float f) {
    unsigned int u = __float_as_uint(f);
    u = (u + 0x7FFFu + ((u >> 16) & 1u)) >> 16;   // RNE
    return (unsigned short)u;
}
static __device__ __forceinline__ float b2f(unsigned short h) {
    return __uint_as_float((unsigned int)h << 16);
}
static __device__ __forceinline__ float blo(unsigned int v) {
    return __uint_as_float(v << 16);
}
static __device__ __forceinline__ float bhi(unsigned int v) {
    return __uint_as_float(v & 0xFFFF0000u);
}

// ========== pass 1: per-block histogram over 196 coarse buckets ==========
__global__ __launch_bounds__(256) void k_p1hist(const int* __restrict__ dst,
                                                int* __restrict__ mat) {
    __shared__ int h[NBUK];
    const int t = threadIdx.x, blk = blockIdx.x;
    for (int i = t; i < NBUK; i += 256) h[i] = 0;
    __syncthreads();
    int beg4 = blk * (EPB / 4);
    int end4 = beg4 + EPB / 4;
    if (end4 > NE / 4) end4 = NE / 4;
    for (int i = beg4 + t; i < end4; i += 256) {
        const int4 d = ((const int4*)dst)[i];
        atomicAdd(&h[d.x >> 9], 1);
        atomicAdd(&h[d.y >> 9], 1);
        atomicAdd(&h[d.z >> 9], 1);
        atomicAdd(&h[d.w >> 9], 1);
    }
    __syncthreads();
    for (int b = t; b < NBUK; b += 256) mat[b * PB + blk] = h[b];
}

// ================= generic scans (for the 50176-entry matrix) =========
__global__ __launch_bounds__(256) void k_scan1(const int* __restrict__ cnt,
                                               int* __restrict__ bsum, int n) {
    __shared__ int lds[256];
    int base = blockIdx.x * 1024;
    int t = threadIdx.x;
    int s = 0;
#pragma unroll
    for (int u = 0; u < 4; ++u) {
        int i = base + t * 4 + u;
        if (i < n) s += cnt[i];
    }
    lds[t] = s;
    __syncthreads();
    for (int w = 128; w > 0; w >>= 1) {
        if (t < w) lds[t] += lds[t + w];
        __syncthreads();
    }
    if (t == 0) bsum[blockIdx.x] = lds[0];
}

__global__ __launch_bounds__(128) void k_scan2(int* __restrict__ bsum, int nb) {
    __shared__ int lds[128];
    int t = threadIdx.x;
    lds[t] = (t < nb) ? bsum[t] : 0;
    __syncthreads();
    for (int d = 1; d < 128; d <<= 1) {
        int v = (t >= d) ? lds[t - d] : 0;
        __syncthreads();
        lds[t] += v;
        __syncthreads();
    }
    if (t < nb) bsum[t] = (t == 0) ? 0 : lds[t - 1];
}

__global__ __launch_bounds__(256) void k_scan3(const int* __restrict__ cnt,
                                               const int* __restrict__ bsum,
                                               int* __restrict__ off, int n) {
    __shared__ int lds[256];
    int base = blockIdx.x * 1024;
    int t = threadIdx.x;
    int v[4];
    int s = 0;
#pragma unroll
    for (int u = 0; u < 4; ++u) {
        int i = base + t * 4 + u;
        v[u] = (i < n) ? cnt[i] : 0;
        s += v[u];
    }
    lds[t] = s;
    __syncthreads();
    for (int d = 1; d < 256; d <<= 1) {
        int x = (t >= d) ? lds[t - d] : 0;
        __syncthreads();
        lds[t] += x;
        __syncthreads();
    }
    int excl = bsum[blockIdx.x] + ((t == 0) ? 0 : lds[t - 1]);
#pragma unroll
    for (int u = 0; u < 4; ++u) {
        int i = base + t * 4 + u;
        if (i < n) off[i] = excl;
        excl += v[u];
    }
    if (blockIdx.x == gridDim.x - 1 && t == 255) off[n] = excl;
}

// ========== pass 1 placement: packed (src | dlocal<<17) into reserved runs ====
__global__ __launch_bounds__(256) void k_p1place(const int* __restrict__ src,
                                                 const int* __restrict__ dst,
                                                 const int* __restrict__ matX,
                                                 unsigned int* __restrict__ P) {
    __shared__ int cur[NBUK];
    const int t = threadIdx.x, blk = blockIdx.x;
    for (int b = t; b < NBUK; b += 256) cur[b] = matX[b * PB + blk];
    __syncthreads();
    int beg4 = blk * (EPB / 4);
    int end4 = beg4 + EPB / 4;
    if (end4 > NE / 4) end4 = NE / 4;
    for (int i = beg4 + t; i < end4; i += 256) {
        const int4 d = ((const int4*)dst)[i];
        const int4 s = ((const int4*)src)[i];
        int p0 = atomicAdd(&cur[d.x >> 9], 1);
        int p1 = atomicAdd(&cur[d.y >> 9], 1);
        int p2 = atomicAdd(&cur[d.z >> 9], 1);
        int p3 = atomicAdd(&cur[d.w >> 9], 1);
        P[p0] = (unsigned)s.x | ((unsigned)(d.x & 511) << 17);
        P[p1] = (unsigned)s.y | ((unsigned)(d.y & 511) << 17);
        P[p2] = (unsigned)s.z | ((unsigned)(d.z & 511) << 17);
        P[p3] = (unsigned)s.w | ((unsigned)(d.w & 511) << 17);
    }
}

// ========== merged: pass-2 LDS counting sort (blocks 0..195)  +  GEMM1 ========
__global__ __launch_bounds__(256) void k_sort2_mfma1(const unsigned int* __restrict__ P,
                                                     const int* __restrict__ matX,
                                                     int* __restrict__ esrc,
                                                     int* __restrict__ off,
                                                     const float* __restrict__ feat,
                                                     const float* __restrict__ Ws,
                                                     const float* __restrict__ Wn,
                                                     const float* __restrict__ b,
                                                     unsigned short* __restrict__ C1) {
    __shared__ char smem[16384];
    const int tid = threadIdx.x;

    if (blockIdx.x < NBUK) {
        // ---- sort role ----
        const int bb = blockIdx.x;
        int* cnt = (int*)smem;            // [512] counts, later cursor
        int* sA  = (int*)(smem + 2048);   // [512]
        int* sB  = (int*)(smem + 4096);   // [512]
        const int beg = matX[bb * PB];
        const int end = matX[(bb + 1) * PB];

        for (int i = tid; i < 512; i += 256) cnt[i] = 0;
        __syncthreads();
        for (int i = beg + tid; i < end; i += 256)
            atomicAdd(&cnt[P[i] >> 17], 1);
        __syncthreads();
        for (int i = tid; i < 512; i += 256) sA[i] = cnt[i];
        __syncthreads();
        int* pin = sA; int* pout = sB;
        for (int d = 1; d < 512; d <<= 1) {
            for (int i = tid; i < 512; i += 256)
                pout[i] = pin[i] + (i >= d ? pin[i - d] : 0);
            __syncthreads();
            int* tmp = pin; pin = pout; pout = tmp;
        }
        const int nodes = (bb == NBUK - 1) ? (NN - (NBUK - 1) * 512) : 512;
        for (int i = tid; i < 512; i += 256) {
            int ex = i ? pin[i - 1] : 0;
            cnt[i] = ex;
            if (i < nodes) off[bb * 512 + i] = beg + ex;
        }
        if (bb == NBUK - 1 && tid == 0) off[NN] = NE;
        __syncthreads();
        for (int i = beg + tid; i < end; i += 256) {
            unsigned v = P[i];
            int dl = (int)(v >> 17);
            int pos = atomicAdd(&cnt[dl], 1);
            esrc[beg + pos] = (int)(v & 0x1FFFFu);
        }
        return;
    }

    // ---- mfma1 role ----
    unsigned short* Bl = (unsigned short*)smem;  // [16*64*8] 16KB
    const int mid = blockIdx.x - NBUK;

    for (int idx = tid; idx < 16 * 64; idx += 256) {
        int frag = idx >> 6, le = idx & 63;
        int ct = frag >> 1, kt = frag & 1;
        int col = ct * 16 + (le & 15);
        int kb  = kt * 32 + (le >> 4) * 8;
        unsigned short tmp[8];
#pragma unroll
        for (int j = 0; j < 8; ++j) {
            int k = kb + j;
            float w = (col < 64) ? Ws[k * 64 + col] : Wn[k * 64 + (col - 64)];
            tmp[j] = f2b(w);
        }
        uint4 pk;
        pk.x = (unsigned)tmp[0] | ((unsigned)tmp[1] << 16);
        pk.y = (unsigned)tmp[2] | ((unsigned)tmp[3] << 16);
        pk.z = (unsigned)tmp[4] | ((unsigned)tmp[5] << 16);
        pk.w = (unsigned)tmp[6] | ((unsigned)tmp[7] << 16);
        *(uint4*)(&Bl[idx * 8]) = pk;
    }
    __syncthreads();

    const int wave = tid >> 6, lane = tid & 63;
    const int r0 = mid * 64 + wave * 16;

    s16x8 a[2];
#pragma unroll
    for (int kt = 0; kt < 2; ++kt) {
        int row = r0 + (lane & 15);
        if (row >= NN) row = NN - 1;
        int kb = kt * 32 + (lane >> 4) * 8;
        const float4 f0 = *(const float4*)(feat + (size_t)row * 64 + kb);
        const float4 f1 = *(const float4*)(feat + (size_t)row * 64 + kb + 4);
        a[kt][0] = (short)f2b(f0.x); a[kt][1] = (short)f2b(f0.y);
        a[kt][2] = (short)f2b(f0.z); a[kt][3] = (short)f2b(f0.w);
        a[kt][4] = (short)f2b(f1.x); a[kt][5] = (short)f2b(f1.y);
        a[kt][6] = (short)f2b(f1.z); a[kt][7] = (short)f2b(f1.w);
    }

    const s16x8* Bl8 = (const s16x8*)Bl;
#pragma unroll
    for (int ct = 0; ct < 8; ++ct) {
        f32x4 acc = {0.f, 0.f, 0.f, 0.f};
#pragma unroll
        for (int kt = 0; kt < 2; ++kt) {
            s16x8 bf = Bl8[(ct * 2 + kt) * 64 + lane];
            acc = __builtin_amdgcn_mfma_f32_16x16x32_bf16(a[kt], bf, acc, 0, 0, 0);
        }
        int c = ct * 16 + (lane & 15);
        float bias = (c < 64) ? b[c] : 0.f;
#pragma unroll
        for (int q = 0; q < 4; ++q) {
            int r = r0 + (lane >> 4) * 4 + q;
            if (r < NN) C1[(size_t)r * 128 + c] = f2b(acc[q] + bias);
        }
    }
}

// ===== fused: gather-mean layer1 (16 lanes/node, 8B/lane, unroll4)
//       -> LDS h1 tile (swizzled) -> GEMM2 =====
__global__ __launch_bounds__(256) void k_gath1_mfma2(const int* __restrict__ off,
                                                     const int* __restrict__ esrc,
                                                     const unsigned short* __restrict__ C1,
                                                     const float* __restrict__ Ws,
                                                     const float* __restrict__ Wn,
                                                     const float* __restrict__ b,
                                                     float* __restrict__ C2s,
                                                     unsigned short* __restrict__ C2n) {
    __shared__ unsigned short Bl[8 * 64 * 8];  // 8KB weight frags
    __shared__ unsigned short Hl[64 * 64];     // 8KB h1 tile, XOR-swizzled rows
    const int tid = threadIdx.x;

    for (int idx = tid; idx < 8 * 64; idx += 256) {
        int frag = idx >> 6, le = idx & 63;
        int ct = frag >> 1, kt = frag & 1;
        int col = ct * 16 + (le & 15);
        int kb  = kt * 32 + (le >> 4) * 8;
        unsigned short tmp[8];
#pragma unroll
        for (int j = 0; j < 8; ++j) {
            int k = kb + j;
            float w = (col < 32) ? Ws[k * 32 + col] : Wn[k * 32 + (col - 32)];
            tmp[j] = f2b(w);
        }
        uint4 pk;
        pk.x = (unsigned)tmp[0] | ((unsigned)tmp[1] << 16);
        pk.y = (unsigned)tmp[2] | ((unsigned)tmp[3] << 16);
        pk.z = (unsigned)tmp[4] | ((unsigned)tmp[5] << 16);
        pk.w = (unsigned)tmp[6] | ((unsigned)tmp[7] << 16);
        *(uint4*)(&Bl[idx * 8]) = pk;
    }

    const int base = blockIdx.x * 64;
    const int sub = tid & 15;          // 16 lanes/node, 8B each
#pragma unroll 1
    for (int g = 0; g < 4; ++g) {
        int rloc = g * 16 + (tid >> 4);
        int node = base + rloc;
        if (node < NN) {
            int beg = off[node], end = off[node + 1];
            float a0 = 0.f, a1 = 0.f, a2 = 0.f, a3 = 0.f;
            float c0 = 0.f, c1 = 0.f, c2 = 0.f, c3 = 0.f;
            int k = beg;
            for (; k + 3 < end; k += 4) {
                int e0 = esrc[k], e1 = esrc[k + 1], e2 = esrc[k + 2], e3 = esrc[k + 3];
                uint2 v0 = *(const uint2*)(C1 + (size_t)e0 * 128 + 64 + sub * 4);
                uint2 v1 = *(const uint2*)(C1 + (size_t)e1 * 128 + 64 + sub * 4);
                uint2 v2 = *(const uint2*)(C1 + (size_t)e2 * 128 + 64 + sub * 4);
                uint2 v3 = *(const uint2*)(C1 + (size_t)e3 * 128 + 64 + sub * 4);
                a0 += blo(v0.x); a1 += bhi(v0.x); a2 += blo(v0.y); a3 += bhi(v0.y);
                c0 += blo(v1.x); c1 += bhi(v1.x); c2 += blo(v1.y); c3 += bhi(v1.y);
                a0 += blo(v2.x); a1 += bhi(v2.x); a2 += blo(v2.y); a3 += bhi(v2.y);
                c0 += blo(v3.x); c1 += bhi(v3.x); c2 += blo(v3.y); c3 += bhi(v3.y);
            }
            for (; k < end; ++k) {
                int e = esrc[k];
                uint2 v = *(const uint2*)(C1 + (size_t)e * 128 + 64 + sub * 4);
                a0 += blo(v.x); a1 += bhi(v.x); a2 += blo(v.y); a3 += bhi(v.y);
            }
            a0 += c0; a1 += c1; a2 += c2; a3 += c3;
            float inv = (end > beg) ? 1.0f / (float)(end - beg) : 0.f;
            uint2 sv = *(const uint2*)(C1 + (size_t)node * 128 + sub * 4);
            float h0 = blo(sv.x) + a0 * inv;
            float h1v = bhi(sv.x) + a1 * inv;
            float h2 = blo(sv.y) + a2 * inv;
            float h3 = bhi(sv.y) + a3 * inv;
            uint2 w;
            w.x = (unsigned)f2b(h0) | ((unsigned)f2b(h1v) << 16);
            w.y = (unsigned)f2b(h2) | ((unsigned)f2b(h3) << 16);
            int boff = (rloc * 128 + sub * 8) ^ ((rloc & 7) << 4);
            *(uint2*)((char*)Hl + boff) = w;
        }
    }
    __syncthreads();

    const int wave = tid >> 6, lane = tid & 63;
    const int rl = wave * 16 + (lane & 15);

    s16x8 a[2];
#pragma unroll
    for (int kt = 0; kt < 2; ++kt) {
        int boff = rl * 128 + kt * 64 + (lane >> 4) * 16;
        a[kt] = *(const s16x8*)((const char*)Hl + (boff ^ ((rl & 7) << 4)));
    }

    const s16x8* Bl8 = (const s16x8*)Bl;
#pragma unroll
    for (int ct = 0; ct < 4; ++ct) {
        f32x4 acc = {0.f, 0.f, 0.f, 0.f};
#pragma unroll
        for (int kt = 0; kt < 2; ++kt) {
            s16x8 bf = Bl8[(ct * 2 + kt) * 64 + lane];
            acc = __builtin_amdgcn_mfma_f32_16x16x32_bf16(a[kt], bf, acc, 0, 0, 0);
        }
        int c = ct * 16 + (lane & 15);
#pragma unroll
        for (int q = 0; q < 4; ++q) {
            int r = blockIdx.x * 64 + wave * 16 + (lane >> 4) * 4 + q;
            if (r < NN) {
                if (c < 32) C2s[(size_t)r * 32 + c] = acc[q] + b[c];
                else        C2n[(size_t)r * 32 + (c - 32)] = f2b(acc[q]);
            }
        }
    }
}

// ===== gather 2: 8 lanes/node (8B/lane), unroll4; out = C2s + mean(C2n) =====
__global__ __launch_bounds__(256) void k_gath2(const int* __restrict__ off,
                                               const int* __restrict__ esrc,
                                               const float* __restrict__ C2s,
                                               const unsigned short* __restrict__ C2n,
                                               float* __restrict__ out) {
    int node = blockIdx.x * 32 + (threadIdx.x >> 3);
    int sub  = threadIdx.x & 7;
    if (node >= NN) return;
    int beg = off[node], end = off[node + 1];
    float a0 = 0.f, a1 = 0.f, a2 = 0.f, a3 = 0.f;
    float c0 = 0.f, c1 = 0.f, c2 = 0.f, c3 = 0.f;
    int k = beg;
    for (; k + 3 < end; k += 4) {
        int e0 = esrc[k], e1 = esrc[k + 1], e2 = esrc[k + 2], e3 = esrc[k + 3];
        uint2 v0 = *(const uint2*)(C2n + (size_t)e0 * 32 + sub * 4);
        uint2 v1 = *(const uint2*)(C2n + (size_t)e1 * 32 + sub * 4);
        uint2 v2 = *(const uint2*)(C2n + (size_t)e2 * 32 + sub * 4);
        uint2 v3 = *(const uint2*)(C2n + (size_t)e3 * 32 + sub * 4);
        a0 += blo(v0.x); a1 += bhi(v0.x); a2 += blo(v0.y); a3 += bhi(v0.y);
        c0 += blo(v1.x); c1 += bhi(v1.x); c2 += blo(v1.y); c3 += bhi(v1.y);
        a0 += blo(v2.x); a1 += bhi(v2.x); a2 += blo(v2.y); a3 += bhi(v2.y);
        c0 += blo(v3.x); c1 += bhi(v3.x); c2 += blo(v3.y); c3 += bhi(v3.y);
    }
    for (; k < end; ++k) {
        int e = esrc[k];
        uint2 v = *(const uint2*)(C2n + (size_t)e * 32 + sub * 4);
        a0 += blo(v.x); a1 += bhi(v.x); a2 += blo(v.y); a3 += bhi(v.y);
    }
    a0 += c0; a1 += c1; a2 += c2; a3 += c3;
    float inv = (end > beg) ? 1.0f / (float)(end - beg) : 0.f;
    const float4 sv = *(const float4*)(C2s + (size_t)node * 32 + sub * 4);
    float4 o;
    o.x = sv.x + a0 * inv;
    o.y = sv.y + a1 * inv;
    o.z = sv.z + a2 * inv;
    o.w = sv.w + a3 * inv;
    *(float4*)(out + (size_t)node * 32 + sub * 4) = o;
}

extern "C" void kernel_launch(void* const* d_in, const int* in_sizes, int n_in,
                              void* d_out, int out_size, void* d_ws, size_t ws_size,
                              hipStream_t stream) {
    const float* feat    = (const float*)d_in[0];
    const int*   src     = (const int*)d_in[1];
    const int*   dst     = (const int*)d_in[2];
    const float* Wself1  = (const float*)d_in[3];
    const float* Wneigh1 = (const float*)d_in[4];
    const float* b1      = (const float*)d_in[5];
    const float* Wself2  = (const float*)d_in[6];
    const float* Wneigh2 = (const float*)d_in[7];
    const float* b2      = (const float*)d_in[8];
    float* out = (float*)d_out;

    char* ws = (char*)d_ws;
    size_t offb = 0;
    auto alloc = [&](size_t bytes) -> void* {
        void* p = ws + offb;
        offb += (bytes + 255) & ~(size_t)255;
        return p;
    };
    int*            mat  = (int*)alloc((size_t)MAT * sizeof(int));
    int*            matX = (int*)alloc((size_t)(MAT + 1) * sizeof(int));
    int*            bsum = (int*)alloc(128 * sizeof(int));
    unsigned int*   P    = (unsigned int*)alloc((size_t)NE * sizeof(int));
    int*            esrc = (int*)alloc((size_t)NE * sizeof(int));
    int*            off  = (int*)alloc((size_t)(NN + 1) * sizeof(int));
    unsigned short* C1   = (unsigned short*)alloc((size_t)NN * 128 * 2);
    float*          C2s  = (float*)alloc((size_t)NN * 32 * sizeof(float));
    unsigned short* C2n  = (unsigned short*)alloc((size_t)NN * 32 * 2);

    // ---- CSR build: two-pass LDS counting sort (no global atomics) ----
    k_p1hist<<<PB, 256, 0, stream>>>(dst, mat);
    k_scan1<<<MAT / 1024, 256, 0, stream>>>(mat, bsum, MAT);
    k_scan2<<<1, 128, 0, stream>>>(bsum, MAT / 1024);
    k_scan3<<<MAT / 1024, 256, 0, stream>>>(mat, bsum, matX, MAT);
    k_p1place<<<PB, 256, 0, stream>>>(src, dst, matX, P);

    // ---- pass-2 sort (196 blocks) + layer-1 GEMM (1563 blocks), one dispatch ----
    k_sort2_mfma1<<<NBUK + NBM, 256, 0, stream>>>(P, matX, esrc, off,
                                                  feat, Wself1, Wneigh1, b1, C1);

    // ---- layer-1 gather + layer-2 GEMM fused; then layer-2 gather ----
    k_gath1_mfma2<<<(NN + 63) / 64, 256, 0, stream>>>(off, esrc, C1, Wself2, Wneigh2, b2, C2s, C2n);
    k_gath2<<<(NN + 31) / 32, 256, 0, stream>>>(off, esrc, C2s, C2n, out);
}

// Round 8
// 97.009 us; speedup vs baseline: 18.7100x; 1.1316x over previous
//
#include <hip/hip_runtime.h>

constexpr int NN    = 100000;
constexpr int NE    = 1200000;

constexpr int NBUK = 196;                 // coarse bucket = dst >> 9
constexpr int PB   = 256;                 // pass-1 blocks
constexpr int EPB  = (NE + PB - 1) / PB;  // 4688 edges / p1 block
constexpr int MAT  = NBUK * PB;           // 50176
constexpr int NBM  = (NN + 63) / 64;      // 1563 mfma1 blocks

typedef float  f32x4 __attribute__((ext_vector_type(4)));
typedef short  s16x8 __attribute__((ext_vector_type(8)));

static __device__ __forceinline__ unsigned short f2b(float f) {
    unsigned int u = __float_as_uint(f);
    u = (u + 0x7FFFu + ((u >> 16) & 1u)) >> 16;   // RNE
    return (unsigned short)u;
}
static __device__ __forceinline__ float blo(unsigned int v) {
    return __uint_as_float(v << 16);
}
static __device__ __forceinline__ float bhi(unsigned int v) {
    return __uint_as_float(v & 0xFFFF0000u);
}

// ========== pass 1: per-block histogram over 196 coarse buckets ==========
__global__ __launch_bounds__(256) void k_p1hist(const int* __restrict__ dst,
                                                int* __restrict__ mat) {
    __shared__ int h[NBUK];
    const int t = threadIdx.x, blk = blockIdx.x;
    for (int i = t; i < NBUK; i += 256) h[i] = 0;
    __syncthreads();
    int beg4 = blk * (EPB / 4);
    int end4 = beg4 + EPB / 4;
    if (end4 > NE / 4) end4 = NE / 4;
    for (int i = beg4 + t; i < end4; i += 256) {
        const int4 d = ((const int4*)dst)[i];
        atomicAdd(&h[d.x >> 9], 1);
        atomicAdd(&h[d.y >> 9], 1);
        atomicAdd(&h[d.z >> 9], 1);
        atomicAdd(&h[d.w >> 9], 1);
    }
    __syncthreads();
    for (int b = t; b < NBUK; b += 256) mat[b * PB + blk] = h[b];
}

// ===== scanA: per-bucket-row exclusive scan (196 blocks) + row totals T =====
__global__ __launch_bounds__(256) void k_scanA(const int* __restrict__ mat,
                                               int* __restrict__ matX,
                                               int* __restrict__ T) {
    __shared__ int lds[256];
    const int b = blockIdx.x, t = threadIdx.x;
    int v = mat[b * 256 + t];
    lds[t] = v;
    __syncthreads();
    for (int d = 1; d < 256; d <<= 1) {
        int x = (t >= d) ? lds[t - d] : 0;
        __syncthreads();
        lds[t] += x;
        __syncthreads();
    }
    matX[b * 256 + t] = lds[t] - v;          // exclusive within row
    if (t == 255) T[b] = lds[255];
}

// ===== scanB: add bucket base (every block rescans the 196 totals) =====
__global__ __launch_bounds__(256) void k_scanB(const int* __restrict__ T,
                                               int* __restrict__ matX) {
    __shared__ int lds[256];
    const int b = blockIdx.x, t = threadIdx.x;
    lds[t] = (t < NBUK) ? T[t] : 0;
    __syncthreads();
    for (int d = 1; d < 256; d <<= 1) {
        int x = (t >= d) ? lds[t - d] : 0;
        __syncthreads();
        lds[t] += x;
        __syncthreads();
    }
    int base = (b == 0) ? 0 : lds[b - 1];
    matX[b * 256 + t] += base;
    if (b == 0 && t == 0) matX[MAT] = NE;
}

// ========== pass 1 placement: packed (src | dlocal<<17) into reserved runs ====
__global__ __launch_bounds__(256) void k_p1place(const int* __restrict__ src,
                                                 const int* __restrict__ dst,
                                                 const int* __restrict__ matX,
                                                 unsigned int* __restrict__ P) {
    __shared__ int cur[NBUK];
    const int t = threadIdx.x, blk = blockIdx.x;
    for (int b = t; b < NBUK; b += 256) cur[b] = matX[b * PB + blk];
    __syncthreads();
    int beg4 = blk * (EPB / 4);
    int end4 = beg4 + EPB / 4;
    if (end4 > NE / 4) end4 = NE / 4;
    for (int i = beg4 + t; i < end4; i += 256) {
        const int4 d = ((const int4*)dst)[i];
        const int4 s = ((const int4*)src)[i];
        int p0 = atomicAdd(&cur[d.x >> 9], 1);
        int p1 = atomicAdd(&cur[d.y >> 9], 1);
        int p2 = atomicAdd(&cur[d.z >> 9], 1);
        int p3 = atomicAdd(&cur[d.w >> 9], 1);
        P[p0] = (unsigned)s.x | ((unsigned)(d.x & 511) << 17);
        P[p1] = (unsigned)s.y | ((unsigned)(d.y & 511) << 17);
        P[p2] = (unsigned)s.z | ((unsigned)(d.z & 511) << 17);
        P[p3] = (unsigned)s.w | ((unsigned)(d.w & 511) << 17);
    }
}

// ========== merged: pass-2 LDS counting sort (blocks 0..195)  +  GEMM1 ========
__global__ __launch_bounds__(256) void k_sort2_mfma1(const unsigned int* __restrict__ P,
                                                     const int* __restrict__ matX,
                                                     int* __restrict__ esrc,
                                                     int* __restrict__ off,
                                                     const float* __restrict__ feat,
                                                     const float* __restrict__ Ws,
                                                     const float* __restrict__ Wn,
                                                     const float* __restrict__ b,
                                                     unsigned short* __restrict__ C1) {
    __shared__ char smem[16384];
    const int tid = threadIdx.x;

    if (blockIdx.x < NBUK) {
        // ---- sort role ----
        const int bb = blockIdx.x;
        int* cnt = (int*)smem;            // [512] counts, later cursor
        int* sA  = (int*)(smem + 2048);   // [512]
        int* sB  = (int*)(smem + 4096);   // [512]
        const int beg = matX[bb * PB];
        const int end = matX[(bb + 1) * PB];

        for (int i = tid; i < 512; i += 256) cnt[i] = 0;
        __syncthreads();
        for (int i = beg + tid; i < end; i += 256)
            atomicAdd(&cnt[P[i] >> 17], 1);
        __syncthreads();
        for (int i = tid; i < 512; i += 256) sA[i] = cnt[i];
        __syncthreads();
        int* pin = sA; int* pout = sB;
        for (int d = 1; d < 512; d <<= 1) {
            for (int i = tid; i < 512; i += 256)
                pout[i] = pin[i] + (i >= d ? pin[i - d] : 0);
            __syncthreads();
            int* tmp = pin; pin = pout; pout = tmp;
        }
        const int nodes = (bb == NBUK - 1) ? (NN - (NBUK - 1) * 512) : 512;
        for (int i = tid; i < 512; i += 256) {
            int ex = i ? pin[i - 1] : 0;
            cnt[i] = ex;
            if (i < nodes) off[bb * 512 + i] = beg + ex;
        }
        if (bb == NBUK - 1 && tid == 0) off[NN] = NE;
        __syncthreads();
        for (int i = beg + tid; i < end; i += 256) {
            unsigned v = P[i];
            int dl = (int)(v >> 17);
            int pos = atomicAdd(&cnt[dl], 1);
            esrc[beg + pos] = (int)(v & 0x1FFFFu);
        }
        return;
    }

    // ---- mfma1 role ----
    unsigned short* Bl = (unsigned short*)smem;  // [16*64*8] 16KB
    const int mid = blockIdx.x - NBUK;

    for (int idx = tid; idx < 16 * 64; idx += 256) {
        int frag = idx >> 6, le = idx & 63;
        int ct = frag >> 1, kt = frag & 1;
        int col = ct * 16 + (le & 15);
        int kb  = kt * 32 + (le >> 4) * 8;
        unsigned short tmp[8];
#pragma unroll
        for (int j = 0; j < 8; ++j) {
            int k = kb + j;
            float w = (col < 64) ? Ws[k * 64 + col] : Wn[k * 64 + (col - 64)];
            tmp[j] = f2b(w);
        }
        uint4 pk;
        pk.x = (unsigned)tmp[0] | ((unsigned)tmp[1] << 16);
        pk.y = (unsigned)tmp[2] | ((unsigned)tmp[3] << 16);
        pk.z = (unsigned)tmp[4] | ((unsigned)tmp[5] << 16);
        pk.w = (unsigned)tmp[6] | ((unsigned)tmp[7] << 16);
        *(uint4*)(&Bl[idx * 8]) = pk;
    }
    __syncthreads();

    const int wave = tid >> 6, lane = tid & 63;
    const int r0 = mid * 64 + wave * 16;

    s16x8 a[2];
#pragma unroll
    for (int kt = 0; kt < 2; ++kt) {
        int row = r0 + (lane & 15);
        if (row >= NN) row = NN - 1;
        int kb = kt * 32 + (lane >> 4) * 8;
        const float4 f0 = *(const float4*)(feat + (size_t)row * 64 + kb);
        const float4 f1 = *(const float4*)(feat + (size_t)row * 64 + kb + 4);
        a[kt][0] = (short)f2b(f0.x); a[kt][1] = (short)f2b(f0.y);
        a[kt][2] = (short)f2b(f0.z); a[kt][3] = (short)f2b(f0.w);
        a[kt][4] = (short)f2b(f1.x); a[kt][5] = (short)f2b(f1.y);
        a[kt][6] = (short)f2b(f1.z); a[kt][7] = (short)f2b(f1.w);
    }

    const s16x8* Bl8 = (const s16x8*)Bl;
#pragma unroll
    for (int ct = 0; ct < 8; ++ct) {
        f32x4 acc = {0.f, 0.f, 0.f, 0.f};
#pragma unroll
        for (int kt = 0; kt < 2; ++kt) {
            s16x8 bf = Bl8[(ct * 2 + kt) * 64 + lane];
            acc = __builtin_amdgcn_mfma_f32_16x16x32_bf16(a[kt], bf, acc, 0, 0, 0);
        }
        int c = ct * 16 + (lane & 15);
        float bias = (c < 64) ? b[c] : 0.f;
#pragma unroll
        for (int q = 0; q < 4; ++q) {
            int r = r0 + (lane >> 4) * 4 + q;
            if (r < NN) C1[(size_t)r * 128 + c] = f2b(acc[q] + bias);
        }
    }
}

// ===== fused: gather-mean layer1 (8 lanes/node, 16B/lane, unroll4)
//       -> LDS h1 tile (swizzled) -> GEMM2 =====
__global__ __launch_bounds__(256) void k_gath1_mfma2(const int* __restrict__ off,
                                                     const int* __restrict__ esrc,
                                                     const unsigned short* __restrict__ C1,
                                                     const float* __restrict__ Ws,
                                                     const float* __restrict__ Wn,
                                                     const float* __restrict__ b,
                                                     float* __restrict__ C2s,
                                                     unsigned short* __restrict__ C2n) {
    __shared__ unsigned short Bl[8 * 64 * 8];  // 8KB weight frags
    __shared__ unsigned short Hl[64 * 64];     // 8KB h1 tile, XOR-swizzled rows
    const int tid = threadIdx.x;

    for (int idx = tid; idx < 8 * 64; idx += 256) {
        int frag = idx >> 6, le = idx & 63;
        int ct = frag >> 1, kt = frag & 1;
        int col = ct * 16 + (le & 15);
        int kb  = kt * 32 + (le >> 4) * 8;
        unsigned short tmp[8];
#pragma unroll
        for (int j = 0; j < 8; ++j) {
            int k = kb + j;
            float w = (col < 32) ? Ws[k * 32 + col] : Wn[k * 32 + (col - 32)];
            tmp[j] = f2b(w);
        }
        uint4 pk;
        pk.x = (unsigned)tmp[0] | ((unsigned)tmp[1] << 16);
        pk.y = (unsigned)tmp[2] | ((unsigned)tmp[3] << 16);
        pk.z = (unsigned)tmp[4] | ((unsigned)tmp[5] << 16);
        pk.w = (unsigned)tmp[6] | ((unsigned)tmp[7] << 16);
        *(uint4*)(&Bl[idx * 8]) = pk;
    }

    const int base = blockIdx.x * 64;
    const int sub = tid & 7;           // 8 lanes/node, 16B each
#pragma unroll 1
    for (int g = 0; g < 2; ++g) {
        int rloc = g * 32 + (tid >> 3);
        int node = base + rloc;
        if (node < NN) {
            int beg = off[node], end = off[node + 1];
            float a0 = 0.f, a1 = 0.f, a2 = 0.f, a3 = 0.f;
            float a4 = 0.f, a5 = 0.f, a6 = 0.f, a7 = 0.f;
            float c0 = 0.f, c1 = 0.f, c2 = 0.f, c3 = 0.f;
            float c4 = 0.f, c5 = 0.f, c6 = 0.f, c7 = 0.f;
            int k = beg;
            for (; k + 3 < end; k += 4) {
                int e0 = esrc[k], e1 = esrc[k + 1], e2 = esrc[k + 2], e3 = esrc[k + 3];
                uint4 v0 = *(const uint4*)(C1 + (size_t)e0 * 128 + 64 + sub * 8);
                uint4 v1 = *(const uint4*)(C1 + (size_t)e1 * 128 + 64 + sub * 8);
                uint4 v2 = *(const uint4*)(C1 + (size_t)e2 * 128 + 64 + sub * 8);
                uint4 v3 = *(const uint4*)(C1 + (size_t)e3 * 128 + 64 + sub * 8);
                a0 += blo(v0.x); a1 += bhi(v0.x); a2 += blo(v0.y); a3 += bhi(v0.y);
                a4 += blo(v0.z); a5 += bhi(v0.z); a6 += blo(v0.w); a7 += bhi(v0.w);
                c0 += blo(v1.x); c1 += bhi(v1.x); c2 += blo(v1.y); c3 += bhi(v1.y);
                c4 += blo(v1.z); c5 += bhi(v1.z); c6 += blo(v1.w); c7 += bhi(v1.w);
                a0 += blo(v2.x); a1 += bhi(v2.x); a2 += blo(v2.y); a3 += bhi(v2.y);
                a4 += blo(v2.z); a5 += bhi(v2.z); a6 += blo(v2.w); a7 += bhi(v2.w);
                c0 += blo(v3.x); c1 += bhi(v3.x); c2 += blo(v3.y); c3 += bhi(v3.y);
                c4 += blo(v3.z); c5 += bhi(v3.z); c6 += blo(v3.w); c7 += bhi(v3.w);
            }
            for (; k < end; ++k) {
                int e = esrc[k];
                uint4 v = *(const uint4*)(C1 + (size_t)e * 128 + 64 + sub * 8);
                a0 += blo(v.x); a1 += bhi(v.x); a2 += blo(v.y); a3 += bhi(v.y);
                a4 += blo(v.z); a5 += bhi(v.z); a6 += blo(v.w); a7 += bhi(v.w);
            }
            a0 += c0; a1 += c1; a2 += c2; a3 += c3;
            a4 += c4; a5 += c5; a6 += c6; a7 += c7;
            float inv = (end > beg) ? 1.0f / (float)(end - beg) : 0.f;
            uint4 sv = *(const uint4*)(C1 + (size_t)node * 128 + sub * 8);
            uint4 w;
            w.x = (unsigned)f2b(blo(sv.x) + a0 * inv) | ((unsigned)f2b(bhi(sv.x) + a1 * inv) << 16);
            w.y = (unsigned)f2b(blo(sv.y) + a2 * inv) | ((unsigned)f2b(bhi(sv.y) + a3 * inv) << 16);
            w.z = (unsigned)f2b(blo(sv.z) + a4 * inv) | ((unsigned)f2b(bhi(sv.z) + a5 * inv) << 16);
            w.w = (unsigned)f2b(blo(sv.w) + a6 * inv) | ((unsigned)f2b(bhi(sv.w) + a7 * inv) << 16);
            int boff = (rloc * 128 + sub * 16) ^ ((rloc & 7) << 4);
            *(uint4*)((char*)Hl + boff) = w;
        }
    }
    __syncthreads();

    const int wave = tid >> 6, lane = tid & 63;
    const int rl = wave * 16 + (lane & 15);

    s16x8 a[2];
#pragma unroll
    for (int kt = 0; kt < 2; ++kt) {
        int boff = rl * 128 + kt * 64 + (lane >> 4) * 16;
        a[kt] = *(const s16x8*)((const char*)Hl + (boff ^ ((rl & 7) << 4)));
    }

    const s16x8* Bl8 = (const s16x8*)Bl;
#pragma unroll
    for (int ct = 0; ct < 4; ++ct) {
        f32x4 acc = {0.f, 0.f, 0.f, 0.f};
#pragma unroll
        for (int kt = 0; kt < 2; ++kt) {
            s16x8 bf = Bl8[(ct * 2 + kt) * 64 + lane];
            acc = __builtin_amdgcn_mfma_f32_16x16x32_bf16(a[kt], bf, acc, 0, 0, 0);
        }
        int c = ct * 16 + (lane & 15);
#pragma unroll
        for (int q = 0; q < 4; ++q) {
            int r = blockIdx.x * 64 + wave * 16 + (lane >> 4) * 4 + q;
            if (r < NN) {
                if (c < 32) C2s[(size_t)r * 32 + c] = acc[q] + b[c];
                else        C2n[(size_t)r * 32 + (c - 32)] = f2b(acc[q]);
            }
        }
    }
}

// ===== gather 2: 4 lanes/node (16B/lane), unroll4; out = C2s + mean(C2n) =====
__global__ __launch_bounds__(256) void k_gath2(const int* __restrict__ off,
                                               const int* __restrict__ esrc,
                                               const float* __restrict__ C2s,
                                               const unsigned short* __restrict__ C2n,
                                               float* __restrict__ out) {
    int node = blockIdx.x * 64 + (threadIdx.x >> 2);
    int sub  = threadIdx.x & 3;
    if (node >= NN) return;
    int beg = off[node], end = off[node + 1];
    float a0 = 0.f, a1 = 0.f, a2 = 0.f, a3 = 0.f;
    float a4 = 0.f, a5 = 0.f, a6 = 0.f, a7 = 0.f;
    float c0 = 0.f, c1 = 0.f, c2 = 0.f, c3 = 0.f;
    float c4 = 0.f, c5 = 0.f, c6 = 0.f, c7 = 0.f;
    int k = beg;
    for (; k + 3 < end; k += 4) {
        int e0 = esrc[k], e1 = esrc[k + 1], e2 = esrc[k + 2], e3 = esrc[k + 3];
        uint4 v0 = *(const uint4*)(C2n + (size_t)e0 * 32 + sub * 8);
        uint4 v1 = *(const uint4*)(C2n + (size_t)e1 * 32 + sub * 8);
        uint4 v2 = *(const uint4*)(C2n + (size_t)e2 * 32 + sub * 8);
        uint4 v3 = *(const uint4*)(C2n + (size_t)e3 * 32 + sub * 8);
        a0 += blo(v0.x); a1 += bhi(v0.x); a2 += blo(v0.y); a3 += bhi(v0.y);
        a4 += blo(v0.z); a5 += bhi(v0.z); a6 += blo(v0.w); a7 += bhi(v0.w);
        c0 += blo(v1.x); c1 += bhi(v1.x); c2 += blo(v1.y); c3 += bhi(v1.y);
        c4 += blo(v1.z); c5 += bhi(v1.z); c6 += blo(v1.w); c7 += bhi(v1.w);
        a0 += blo(v2.x); a1 += bhi(v2.x); a2 += blo(v2.y); a3 += bhi(v2.y);
        a4 += blo(v2.z); a5 += bhi(v2.z); a6 += blo(v2.w); a7 += bhi(v2.w);
        c0 += blo(v3.x); c1 += bhi(v3.x); c2 += blo(v3.y); c3 += bhi(v3.y);
        c4 += blo(v3.z); c5 += bhi(v3.z); c6 += blo(v3.w); c7 += bhi(v3.w);
    }
    for (; k < end; ++k) {
        int e = esrc[k];
        uint4 v = *(const uint4*)(C2n + (size_t)e * 32 + sub * 8);
        a0 += blo(v.x); a1 += bhi(v.x); a2 += blo(v.y); a3 += bhi(v.y);
        a4 += blo(v.z); a5 += bhi(v.z); a6 += blo(v.w); a7 += bhi(v.w);
    }
    a0 += c0; a1 += c1; a2 += c2; a3 += c3;
    a4 += c4; a5 += c5; a6 += c6; a7 += c7;
    float inv = (end > beg) ? 1.0f / (float)(end - beg) : 0.f;
    const float4 s0 = *(const float4*)(C2s + (size_t)node * 32 + sub * 8);
    const float4 s1 = *(const float4*)(C2s + (size_t)node * 32 + sub * 8 + 4);
    float4 o0, o1;
    o0.x = s0.x + a0 * inv; o0.y = s0.y + a1 * inv;
    o0.z = s0.z + a2 * inv; o0.w = s0.w + a3 * inv;
    o1.x = s1.x + a4 * inv; o1.y = s1.y + a5 * inv;
    o1.z = s1.z + a6 * inv; o1.w = s1.w + a7 * inv;
    *(float4*)(out + (size_t)node * 32 + sub * 8) = o0;
    *(float4*)(out + (size_t)node * 32 + sub * 8 + 4) = o1;
}

extern "C" void kernel_launch(void* const* d_in, const int* in_sizes, int n_in,
                              void* d_out, int out_size, void* d_ws, size_t ws_size,
                              hipStream_t stream) {
    const float* feat    = (const float*)d_in[0];
    const int*   src     = (const int*)d_in[1];
    const int*   dst     = (const int*)d_in[2];
    const float* Wself1  = (const float*)d_in[3];
    const float* Wneigh1 = (const float*)d_in[4];
    const float* b1      = (const float*)d_in[5];
    const float* Wself2  = (const float*)d_in[6];
    const float* Wneigh2 = (const float*)d_in[7];
    const float* b2      = (const float*)d_in[8];
    float* out = (float*)d_out;

    char* ws = (char*)d_ws;
    size_t offb = 0;
    auto alloc = [&](size_t bytes) -> void* {
        void* p = ws + offb;
        offb += (bytes + 255) & ~(size_t)255;
        return p;
    };
    int*            mat  = (int*)alloc((size_t)MAT * sizeof(int));
    int*            matX = (int*)alloc((size_t)(MAT + 1) * sizeof(int));
    int*            T    = (int*)alloc(256 * sizeof(int));
    unsigned int*   P    = (unsigned int*)alloc((size_t)NE * sizeof(int));
    int*            esrc = (int*)alloc((size_t)NE * sizeof(int));
    int*            off  = (int*)alloc((size_t)(NN + 1) * sizeof(int));
    unsigned short* C1   = (unsigned short*)alloc((size_t)NN * 128 * 2);
    float*          C2s  = (float*)alloc((size_t)NN * 32 * sizeof(float));
    unsigned short* C2n  = (unsigned short*)alloc((size_t)NN * 32 * 2);

    // ---- CSR build: two-pass LDS counting sort (no global atomics) ----
    k_p1hist<<<PB, 256, 0, stream>>>(dst, mat);
    k_scanA<<<NBUK, 256, 0, stream>>>(mat, matX, T);
    k_scanB<<<NBUK, 256, 0, stream>>>(T, matX);
    k_p1place<<<PB, 256, 0, stream>>>(src, dst, matX, P);

    // ---- pass-2 sort (196 blocks) + layer-1 GEMM (1563 blocks), one dispatch ----
    k_sort2_mfma1<<<NBUK + NBM, 256, 0, stream>>>(P, matX, esrc, off,
                                                  feat, Wself1, Wneigh1, b1, C1);

    // ---- layer-1 gather + layer-2 GEMM fused; then layer-2 gather ----
    k_gath1_mfma2<<<(NN + 63) / 64, 256, 0, stream>>>(off, esrc, C1, Wself2, Wneigh2, b2, C2s, C2n);
    k_gath2<<<(NN + 63) / 64, 256, 0, stream>>>(off, esrc, C2s, C2n, out);
}